// Round 7
// baseline (700.721 us; speedup 1.0000x reference)
//
#include <hip/hip_runtime.h>
#include <hip/hip_bf16.h>
#include <cmath>

typedef __hip_bfloat16 bf16;
typedef __attribute__((ext_vector_type(8))) short s16x8;
typedef __attribute__((ext_vector_type(4))) float f32x4;

#define B_   2
#define T_   2048
#define C_   2048
#define H_   16
#define HD_  128
#define RD_  64
#define QLR_ 1536
#define KLR_ 512
#define SCALE_ 0.07216878364870322f   // (128+64)^-0.5

static __device__ __forceinline__ float b2f(bf16 v){ return __bfloat162float(v); }
static __device__ __forceinline__ bf16  f2b(float v){ return __float2bfloat16(v); }
static __device__ __forceinline__ float us2f(unsigned short u){
    union { unsigned short s[2]; float f; } v; v.s[0]=0; v.s[1]=u; return v.f;
}
static __device__ __forceinline__ float ldS(const void* p, size_t i, int isf32){
    return isf32 ? ((const float*)p)[i] : b2f(((const bf16*)p)[i]);
}
static __device__ __forceinline__ void ld4(const void* p, size_t i, int isf32, float* o){
    if (isf32) {
        float4 v = *(const float4*)((const float*)p + i);
        o[0]=v.x; o[1]=v.y; o[2]=v.z; o[3]=v.w;
    } else {
        ushort4 u = *(const ushort4*)((const bf16*)p + i);
        o[0]=us2f(u.x); o[1]=us2f(u.y); o[2]=us2f(u.z); o[3]=us2f(u.w);
    }
}

// ---------------------------------------------------------------------------
// dtype detector (1 = harness buffers are f32, 0 = bf16)
// ---------------------------------------------------------------------------
__global__ __launch_bounds__(64) void detect_kernel(const unsigned short* __restrict__ x,
                                                    int* __restrict__ flag)
{
    int big = 0;
    for (int i = threadIdx.x; i < 1024; i += 64) {
        const unsigned short u = x[2*i];
        const int e = (u >> 7) & 0xFF;
        if (e >= 139) big++;
    }
    #pragma unroll
    for (int off = 32; off; off >>= 1) big += __shfl_down(big, off, 64);
    if (threadIdx.x == 0) *flag = (big > 8) ? 1 : 0;
}

// ---------------------------------------------------------------------------
// Elementwise convert harness buffer -> bf16 (8 elems/thread)
// ---------------------------------------------------------------------------
__global__ __launch_bounds__(256) void convert_kernel(const void* __restrict__ in,
                                                      bf16* __restrict__ out, int n,
                                                      const int* __restrict__ flag)
{
    const int f = *flag;
    const int i0 = (blockIdx.x * 256 + threadIdx.x) * 8;
    if (i0 >= n) return;
    float v[8];
    ld4(in, i0, f, v);
    ld4(in, i0 + 4, f, v + 4);
    bf16* o = out + i0;
    #pragma unroll
    for (int k = 0; k < 8; ++k) o[k] = f2b(v[k]);
}

// ---------------------------------------------------------------------------
// Batched transpose: several harness weights [R][Cc] -> bf16 [Cc][R].
// ---------------------------------------------------------------------------
struct TDesc { const void* in; bf16* out; int R, Cc, blkStart, nx; };
struct TBatch { TDesc d[5]; int nseg; };

__global__ __launch_bounds__(256) void transpose_batch(TBatch tb,
                                                       const int* __restrict__ flag)
{
    const int f = *flag;
    const int bid = blockIdx.x;
    int s = 0;
    #pragma unroll
    for (int i = 1; i < 5; ++i)
        if (i < tb.nseg && bid >= tb.d[i].blkStart) s = i;
    const TDesc d = tb.d[s];
    const int local = bid - d.blkStart;
    const int c0 = (local % d.nx) * 32;
    const int r0 = (local / d.nx) * 32;

    __shared__ float tile[32][33];
    const int tx = threadIdx.x & 31, ty = threadIdx.x >> 5;  // 32 x 8
    #pragma unroll
    for (int i = 0; i < 4; ++i)
        tile[ty + 8*i][tx] = ldS(d.in, (size_t)(r0 + ty + 8*i) * d.Cc + c0 + tx, f);
    __syncthreads();
    #pragma unroll
    for (int i = 0; i < 4; ++i)
        d.out[(size_t)(c0 + ty + 8*i) * d.R + r0 + tx] = f2b(tile[tx][ty + 8*i]);
}

// ---------------------------------------------------------------------------
// Transpose V half of kv [4096][4096] into vT[(b*H+h)*HD + d][t].
// ---------------------------------------------------------------------------
__global__ __launch_bounds__(256) void transpose_v_kernel(const bf16* __restrict__ kvb,
                                                          bf16* __restrict__ vT)
{
    __shared__ bf16 tile[32][34];
    const int c0 = blockIdx.x * 32;        // v-col 0..2047
    const int r0 = blockIdx.y * 32;        // row 0..4095 (b*T + t)
    const int tx = threadIdx.x & 31, ty = threadIdx.x >> 5;
    #pragma unroll
    for (int i = 0; i < 4; ++i)
        tile[ty + 8*i][tx] = kvb[(size_t)(r0 + ty + 8*i) * (H_*256) + H_*128 + c0 + tx];
    __syncthreads();
    const int b  = r0 >> 11;
    const int t0 = r0 & (T_ - 1);
    #pragma unroll
    for (int i = 0; i < 4; ++i) {
        const int c  = c0 + ty + 8*i;
        const int hh = c >> 7, dd = c & 127;
        vT[(((size_t)b*H_ + hh)*HD_ + dd)*T_ + t0 + tx] = tile[tx][ty + 8*i];
    }
}

struct GOuts { void* p[3]; int start[3]; int stride[3]; int nseg; };

// ---------------------------------------------------------------------------
// mfma_gemm v4: 128x128 tile, BK=64, REGISTER-STAGED double-buffer pipeline.
// C[M,N] = A[M,K] @ BT[N,K]^T.  M%128==0, K%128==0 (nkt even), N via ccol<N
// guard; segment starts multiples of 128.
//
// Round-7 rationale: r5 (gload_lds dbuf) and r6 (gload_lds single-buf,
// 3 blk/CU) both land at ~460 TF -> the binder is the per-K-tile vmcnt(0)
// drain on the critical path (gload_lds LDS-DMA aliasing forces it), with
// co-resident blocks phase-locked so cross-block overlap doesn't cover it.
// Fix: stage via registers (global_load -> VGPR -> ds_write). All deps are
// compiler-visible: the wait before ds_write is a COUNTED vmcnt on loads
// issued one full K-tile earlier (latency hidden), and ds_reads can never
// alias VMEM. Barriers are raw s_barrier + lgkmcnt(0) ONLY (no vmcnt drain)
// — the same inline-asm pattern flash_attn already uses successfully with
// loads in flight across it.
//   unroll x2, static rg0/rg1 ping-pong (rule #20: no runtime reg indexing)
//   iter i, half A: GLD(rg1,t+2) | DSW(buf1<-rg0 tile t+1) | CMP(buf0 tile t)
//   iter i, half B: GLD(rg0,t+3) | DSW(buf0<-rg1 tile t+2) | CMP(buf1 tile t+1)
//   1 barrier per K-tile; vmcnt never drained to 0 in the loop.
// VGPR ~200 (rg 64 + acc 64 + frags 40 + addr) @ launch_bounds(256,2): no
// spill risk (cap 256). LDS 2x32KB -> 2 blocks/CU.
// LDS XOR slot-swizzle (verified conflict-free r4-r6), layout identical:
//   write: linear dest tid*16; global source 16B-col = (tid&7)^((tid>>3)&7)
//   read:  physical slot = (ks*4+quad) ^ (l16&7)
// ---------------------------------------------------------------------------
__global__ __launch_bounds__(256, 2) void mfma_gemm(const bf16* __restrict__ A,
                                                    const bf16* __restrict__ BT,
                                                    GOuts go, int N, int K,
                                                    const int* __restrict__ flag, int cH)
{
    __shared__ __align__(16) char smem[65536];
    const int cf   = cH ? *flag : 0;
    const int tid  = threadIdx.x;
    const int lane = tid & 63;
    const int quad = lane >> 4;
    const int l16  = lane & 15;
    const int w    = tid >> 6;
    const int wm   = w >> 1, wn = w & 1;

    // XCD-aware bijective block swizzle (nwg % 8 == 0 for all our grids)
    const int nwg = gridDim.x * gridDim.y;
    const int bid = blockIdx.y * gridDim.x + blockIdx.x;
    const int swz = (bid & 7) * (nwg >> 3) + (bid >> 3);
    const int bm  = (swz / gridDim.x) * 128;
    const int bn  = (swz % gridDim.x) * 128;

    int seg = 0;
    #pragma unroll
    for (int i = 1; i < 3; ++i)
        if (i < go.nseg && bn >= go.start[i]) seg = i;
    void* const dstp   = go.p[seg];
    const int  dstoff  = go.start[seg];
    const int  dstride = go.stride[seg];

    const int nkt = K >> 6;                       // K-tiles of 64; EVEN for all uses

    // staging: linear LDS dest, inverse-swizzled global source (rule 21)
    const int sR   = tid >> 3;                    // row 0..31 within 32-row group
    const int sCol = ((tid & 7) ^ (sR & 7)) * 8;  // bf16 col: slot ^ (row&7)
    const bf16* gA = A  + (size_t)(bm + sR) * K + sCol;
    const bf16* gB = BT + (size_t)(bn + sR) * K + sCol;
    // ds_read swizzle key = row&7 = l16&7 (rows are i*16+l16, 16==0 mod 8)
    const int rxk  = l16 & 7;
    const int aOff = (wm*64 + l16) * 128;
    const int bOff = 16384 + (wn*64 + l16) * 128;

    f32x4 acc[4][4];
    #pragma unroll
    for (int i = 0; i < 4; ++i)
        #pragma unroll
        for (int j = 0; j < 4; ++j)
            acc[i][j] = (f32x4){0.f, 0.f, 0.f, 0.f};

    uint4 rg0[8], rg1[8];

    #define GLD(rg, kt) do {                                                     \
        const int ke_ = ((kt) < nkt ? (kt) : nkt-1) * 64;                        \
        _Pragma("unroll")                                                        \
        for (int j_ = 0; j_ < 4; ++j_)                                           \
            rg[j_]   = *(const uint4*)(gA + (size_t)(j_*32) * K + ke_);          \
        _Pragma("unroll")                                                        \
        for (int j_ = 0; j_ < 4; ++j_)                                           \
            rg[4+j_] = *(const uint4*)(gB + (size_t)(j_*32) * K + ke_);          \
    } while (0)

    #define DSW(buf, rg) do {                                                    \
        _Pragma("unroll")                                                        \
        for (int j_ = 0; j_ < 4; ++j_)                                           \
            *(uint4*)(smem + (buf)*32768 + j_*4096 + tid*16) = rg[j_];           \
        _Pragma("unroll")                                                        \
        for (int j_ = 0; j_ < 4; ++j_)                                           \
            *(uint4*)(smem + (buf)*32768 + 16384 + j_*4096 + tid*16) = rg[4+j_]; \
    } while (0)

    #define CMP(buf) do {                                                        \
        __builtin_amdgcn_s_setprio(1);                                           \
        _Pragma("unroll")                                                        \
        for (int ks_ = 0; ks_ < 2; ++ks_) {                                      \
            s16x8 af_[4];                                                        \
            _Pragma("unroll")                                                    \
            for (int i_ = 0; i_ < 4; ++i_)                                       \
                af_[i_] = *(const s16x8*)(smem + (buf)*32768 + aOff              \
                          + i_*2048 + ((((ks_<<2)|quad) ^ rxk) << 4));           \
            _Pragma("unroll")                                                    \
            for (int j_ = 0; j_ < 4; ++j_) {                                     \
                const s16x8 bf_ = *(const s16x8*)(smem + (buf)*32768 + bOff      \
                          + j_*2048 + ((((ks_<<2)|quad) ^ rxk) << 4));           \
                _Pragma("unroll")                                                \
                for (int i_ = 0; i_ < 4; ++i_)                                   \
                    acc[i_][j_] = __builtin_amdgcn_mfma_f32_16x16x32_bf16(       \
                        af_[i_], bf_, acc[i_][j_], 0, 0, 0);                     \
            }                                                                    \
        }                                                                        \
        __builtin_amdgcn_s_setprio(0);                                           \
    } while (0)

    // lgkm-only barrier: does NOT drain vmcnt -> staged loads stay in flight.
    #define LBAR asm volatile("s_waitcnt lgkmcnt(0)\n\ts_barrier" ::: "memory")

    // prologue: tile0 -> buf0 (one-time full vmcnt wait), tile1 -> rg0
    GLD(rg0, 0);
    DSW(0, rg0);
    GLD(rg0, 1);
    LBAR;

    const int nit = nkt >> 1;
    for (int i = 0; i < nit; ++i) {
        const int t = 2*i;
        // half A: compute tile t (buf0); publish tile t+1; fetch tile t+2
        GLD(rg1, t+2);
        DSW(1, rg0);          // compiler emits counted vmcnt (rg1 stays in flight)
        CMP(0);
        LBAR;
        // half B: compute tile t+1 (buf1); publish tile t+2; fetch tile t+3
        GLD(rg0, t+3);
        DSW(0, rg1);
        CMP(1);
        LBAR;
    }

    #undef GLD
    #undef DSW
    #undef CMP
    #undef LBAR

    #pragma unroll
    for (int i = 0; i < 4; ++i) {
        const int crow = bm + wm*64 + i*16 + quad*4;
        #pragma unroll
        for (int r = 0; r < 4; ++r) {
            #pragma unroll
            for (int j = 0; j < 4; ++j) {
                const int ccol = bn + wn*64 + j*16 + l16;
                if (ccol < N) {
                    const size_t idx = (size_t)(crow + r) * dstride + (ccol - dstoff);
                    if (cf) ((float*)dstp)[idx] = acc[i][j][r];
                    else    ((bf16*)dstp)[idx] = f2b(acc[i][j][r]);
                }
            }
        }
    }
}

// ---------------------------------------------------------------------------
// In-place RMSNorm over rows of X [rows, NPER*256] (internal bf16)
// ---------------------------------------------------------------------------
template<int NPER>
__global__ __launch_bounds__(256) void rms_kernel(bf16* __restrict__ X,
                                                  const void* __restrict__ w,
                                                  const int* __restrict__ flag)
{
    const int wf = *flag;
    const int ncols = NPER * 256;
    __shared__ float red[4];
    const int row = blockIdx.x;
    const int tid = threadIdx.x;
    bf16* xr = X + (size_t)row * ncols;
    float vals[NPER];
    float ss = 0.f;
    #pragma unroll
    for (int i = 0; i < NPER; ++i) {
        float v = b2f(xr[tid + i*256]);
        vals[i] = v; ss += v*v;
    }
    #pragma unroll
    for (int off = 32; off; off >>= 1) ss += __shfl_down(ss, off, 64);
    if ((tid & 63) == 0) red[tid >> 6] = ss;
    __syncthreads();
    const float tot = red[0]+red[1]+red[2]+red[3];
    const float rs  = rsqrtf(tot / (float)ncols + 1e-6f);
    #pragma unroll
    for (int i = 0; i < NPER; ++i) {
        const int c = tid + i*256;
        xr[c] = f2b(vals[i] * rs * ldS(w, c, wf));
    }
}

// ---------------------------------------------------------------------------
// k_pe: in-place RMSNorm over 64 cols + RoPE
// ---------------------------------------------------------------------------
__global__ __launch_bounds__(64) void kpe_rms_rope(bf16* __restrict__ X,
                                                   const void* __restrict__ w,
                                                   const int* __restrict__ flag)
{
    const int wf   = *flag;
    const int row  = blockIdx.x;
    const int t    = row & (T_ - 1);
    const int lane = threadIdx.x;
    bf16* xr = X + (size_t)row * RD_;
    const float v = b2f(xr[lane]);
    float ss = v * v;
    #pragma unroll
    for (int off = 32; off; off >>= 1) ss += __shfl_down(ss, off, 64);
    ss = __shfl(ss, 0, 64);
    const float rs = rsqrtf(ss / 64.f + 1e-6f);
    const float xn = v * rs * ldS(w, lane, wf);
    const int   i  = lane & 31;
    const float freq = powf(10000.f, -(float)(2*i) / 64.f);
    const float ang  = (float)t * freq;
    const float s = sinf(ang), c = cosf(ang);
    const float other = __shfl_xor(xn, 32, 64);
    const float o = (lane < 32) ? (xn * c - other * s) : (other * s + xn * c);
    xr[lane] = f2b(o);
}

// ---------------------------------------------------------------------------
// q_pe RoPE in-place: X [B*T, H*64]
// ---------------------------------------------------------------------------
__global__ __launch_bounds__(256) void qpe_rope(bf16* __restrict__ X)
{
    const int row = blockIdx.x;
    const int t   = row & (T_ - 1);
    bf16* xr = X + (size_t)row * (H_ * RD_);
    const int tid = threadIdx.x;
    #pragma unroll
    for (int pp = 0; pp < 2; ++pp) {
        const int p  = tid + pp * 256;
        const int hh = p >> 5;
        const int i  = p & 31;
        const int i0 = hh * 64 + i;
        const int i1 = i0 + 32;
        const float x1 = b2f(xr[i0]), x2 = b2f(xr[i1]);
        const float freq = powf(10000.f, -(float)(2*i) / 64.f);
        const float ang  = (float)t * freq;
        const float s = sinf(ang), c = cosf(ang);
        xr[i0] = f2b(x1 * c - x2 * s);
        xr[i1] = f2b(x1 * s + x2 * c);
    }
}

// ---------------------------------------------------------------------------
// Flash-style MFMA attention v5 (passing @112.5us, rounds 2-6 verified):
// tight LDS + XOR swizzle (48KB, 3 blocks/CU), spill-free softmax.
// ---------------------------------------------------------------------------
__global__ __launch_bounds__(256, 2) void flash_attn(const bf16* __restrict__ qnop,
                                                     const bf16* __restrict__ qpe,
                                                     const bf16* __restrict__ kv,
                                                     const bf16* __restrict__ kpe,
                                                     const bf16* __restrict__ vT,
                                                     bf16* __restrict__ y)
{
    __shared__ __align__(16) short Klds[64 * 192];
    __shared__ __align__(16) short Vt[128 * 64];
    __shared__ __align__(16) short Plds[4][16 * 64];

    const int h   = blockIdx.x;
    const int qt  = 31 - (int)blockIdx.y;          // heavy blocks dispatched first
    const int b   = blockIdx.z;
    const int q0  = qt * 64;
    const int tid = threadIdx.x;
    const int w    = tid >> 6;
    const int lane = tid & 63;
    const int quad = lane >> 4;
    const int l16  = lane & 15;
    const int rk   = l16 & 7;
    const int rkp  = (l16 ^ (l16 >> 3)) & 7;
    const int row0 = q0 + w * 16;
    const size_t bT = (size_t)b * T_;
    const int bh  = b * H_ + h;

    const int kR = tid >> 4, kS = tid & 15;
    const int pR = tid >> 3, pS = tid & 7;
    const int vD = tid >> 3, vS = tid & 7;

    const bf16* gK = kv  + (bT + kR) * (H_*256) + h*128 + kS*8;
    const bf16* gP = kpe + (bT + pR) * RD_ + pS*8;
    const bf16* gV = vT  + ((size_t)bh*HD_ + vD) * T_ + vS*8;

    short* const wK = &Klds[kR*192 + ((kS ^ (kR & 7)) << 3)];
    short* const wP = &Klds[pR*192 + 128 + ((pS ^ (pR & 7)) << 3)];
    short* const wV = &Vt[vD*64 + ((vS ^ (vD & 7)) << 3)];

    s16x8 aq[6];
    {
        const size_t r = bT + row0 + l16;
        const bf16* qn = qnop + r * (H_*128) + h*128 + quad*8;
        #pragma unroll
        for (int kk = 0; kk < 4; ++kk) aq[kk] = *(const s16x8*)(qn + kk*32);
        const bf16* qp = qpe + r * (H_*64) + h*64 + quad*8;
        aq[4] = *(const s16x8*)(qp);
        aq[5] = *(const s16x8*)(qp + 32);
    }

    f32x4 o[8];
    #pragma unroll
    for (int i = 0; i < 8; ++i) o[i] = (f32x4){0.f,0.f,0.f,0.f};
    float m_run[4] = {-1e30f,-1e30f,-1e30f,-1e30f};
    float l_run[4] = {0.f,0.f,0.f,0.f};

    uint4 k0, k1, k2, k3, p0, p1, v0, v1, v2, v3;
    #define PF(J0) do {                                                     \
        const bf16* a_ = gK + (size_t)(J0) * (H_*256);                      \
        k0 = *(const uint4*)(a_);                                           \
        k1 = *(const uint4*)(a_ + 16*(H_*256));                             \
        k2 = *(const uint4*)(a_ + 32*(H_*256));                             \
        k3 = *(const uint4*)(a_ + 48*(H_*256));                             \
        const bf16* p_ = gP + (size_t)(J0) * RD_;                           \
        p0 = *(const uint4*)(p_);                                           \
        p1 = *(const uint4*)(p_ + 32*RD_);                                  \
        const bf16* v_ = gV + (J0);                                         \
        v0 = *(const uint4*)(v_);                                           \
        v1 = *(const uint4*)(v_ + 32*T_);                                   \
        v2 = *(const uint4*)(v_ + 64*T_);                                   \
        v3 = *(const uint4*)(v_ + 96*T_);                                   \
    } while (0)

    PF(0);

    const int ntiles = qt + 1;
    for (int it = 0; it < ntiles; ++it) {
        const int j0 = it * 64;
        asm volatile("s_waitcnt lgkmcnt(0)\n\ts_barrier" ::: "memory");

        *(uint4*)(wK)          = k0;
        *(uint4*)(wK + 16*192) = k1;
        *(uint4*)(wK + 32*192) = k2;
        *(uint4*)(wK + 48*192) = k3;
        *(uint4*)(wP)          = p0;
        *(uint4*)(wP + 32*192) = p1;
        *(uint4*)(wV)          = v0;
        *(uint4*)(wV + 32*64)  = v1;
        *(uint4*)(wV + 64*64)  = v2;
        *(uint4*)(wV + 96*64)  = v3;

        if (it + 1 < ntiles) PF(j0 + 64);

        asm volatile("s_waitcnt lgkmcnt(0)\n\ts_barrier" ::: "memory");

        if (j0 <= row0 + 15) {
            const bool needmask = (j0 + 63 > row0);
            f32x4 s[4];
            #pragma unroll
            for (int nsub = 0; nsub < 4; ++nsub) {
                f32x4 acc = (f32x4){0.f,0.f,0.f,0.f};
                #pragma unroll
                for (int kk = 0; kk < 6; ++kk) {
                    const s16x8 bk = *(const s16x8*)&Klds[(nsub*16 + l16)*192
                                        + ((((kk << 2) | quad) ^ rk) << 3)];
                    acc = __builtin_amdgcn_mfma_f32_16x16x32_bf16(aq[kk], bk, acc, 0, 0, 0);
                }
                #pragma unroll
                for (int reg = 0; reg < 4; ++reg) acc[reg] *= SCALE_;
                s[nsub] = acc;
            }
            if (needmask) {
                #pragma unroll
                for (int nsub = 0; nsub < 4; ++nsub)
                    #pragma unroll
                    for (int reg = 0; reg < 4; ++reg) {
                        const int col = j0 + nsub*16 + l16;
                        const int row = row0 + quad*4 + reg;
                        if (col > row) s[nsub][reg] = -1e30f;
                    }
            }
            float mt[4], alpha[4], rs[4];
            #pragma unroll
            for (int reg = 0; reg < 4; ++reg)
                mt[reg] = fmaxf(fmaxf(s[0][reg], s[1][reg]), fmaxf(s[2][reg], s[3][reg]));
            #pragma unroll
            for (int d = 1; d < 16; d <<= 1)
                #pragma unroll
                for (int reg = 0; reg < 4; ++reg)
                    mt[reg] = fmaxf(mt[reg], __shfl_xor(mt[reg], d, 64));
            #pragma unroll
            for (int reg = 0; reg < 4; ++reg) {
                const float mnew = fmaxf(m_run[reg], mt[reg]);
                alpha[reg] = __expf(m_run[reg] - mnew);
                m_run[reg] = mnew;
                rs[reg] = 0.f;
            }
            #pragma unroll
            for (int nsub = 0; nsub < 4; ++nsub)
                #pragma unroll
                for (int reg = 0; reg < 4; ++reg) {
                    const float p = __expf(s[nsub][reg] - m_run[reg]);
                    s[nsub][reg] = p;
                    rs[reg] += p;
                }
            #pragma unroll
            for (int d = 1; d < 16; d <<= 1)
                #pragma unroll
                for (int reg = 0; reg < 4; ++reg)
                    rs[reg] += __shfl_xor(rs[reg], d, 64);
            #pragma unroll
            for (int reg = 0; reg < 4; ++reg)
                l_run[reg] = l_run[reg] * alpha[reg] + rs[reg];

            #pragma unroll
            for (int nsub = 0; nsub < 4; ++nsub)
                #pragma unroll
                for (int reg = 0; reg < 4; ++reg) {
                    const bf16 pv = f2b(s[nsub][reg]);
                    const int prow = (quad << 2) + reg;
                    const int pk   = (prow ^ (prow >> 3)) & 7;
                    const int pby  = ((nsub << 5) + (l16 << 1)) ^ (pk << 4);
                    Plds[w][prow*64 + (pby >> 1)] = *(const short*)&pv;
                }
            #pragma unroll
            for (int n2 = 0; n2 < 8; ++n2)
                #pragma unroll
                for (int reg = 0; reg < 4; ++reg)
                    o[n2][reg] *= alpha[reg];

            const s16x8 ap0 = *(const s16x8*)&Plds[w][l16*64 + (((quad    ) ^ rkp) << 3)];
            const s16x8 ap1 = *(const s16x8*)&Plds[w][l16*64 + (((quad | 4) ^ rkp) << 3)];
            #pragma unroll
            for (int n2 = 0; n2 < 8; ++n2) {
                const s16x8 bv0 = *(const s16x8*)&Vt[(n2*16 + l16)*64 + (((quad    ) ^ rk) << 3)];
                const s16x8 bv1 = *(const s16x8*)&Vt[(n2*16 + l16)*64 + (((quad | 4) ^ rk) << 3)];
                o[n2] = __builtin_amdgcn_mfma_f32_16x16x32_bf16(ap0, bv0, o[n2], 0, 0, 0);
                o[n2] = __builtin_amdgcn_mfma_f32_16x16x32_bf16(ap1, bv1, o[n2], 0, 0, 0);
            }
        }
    }
    #undef PF

    #pragma unroll
    for (int reg = 0; reg < 4; ++reg) {
        const float inv = 1.f / l_run[reg];
        const size_t r = bT + row0 + quad*4 + reg;
        bf16* yr = y + r * (H_*128) + h*128 + l16;
        #pragma unroll
        for (int n2 = 0; n2 < 8; ++n2)
            yr[n2*16] = f2b(o[n2][reg] * inv);
    }
}

// ---------------------------------------------------------------------------
extern "C" void kernel_launch(void* const* d_in, const int* in_sizes, int n_in,
                              void* d_out, int out_size, void* d_ws, size_t ws_size,
                              hipStream_t stream)
{
    const void* x         = d_in[0];
    const void* Wq_down   = d_in[1];
    const void* q_norm_w  = d_in[2];
    const void* Wq_up     = d_in[3];
    const void* Wq_pe     = d_in[4];
    const void* Wkv_down  = d_in[5];
    const void* kv_norm_w = d_in[6];
    const void* Wkv_up    = d_in[7];
    const void* Wk_pe     = d_in[8];
    const void* kpe_nw    = d_in[9];
    const void* Wo        = d_in[10];

    char* ws = (char*)d_ws;
    int*  flag = (int*)(ws + 0);
    bf16* xb   = (bf16*)(ws + 256);        // [4096,2048] — dead after x-GEMM; reused as vT
    bf16* cQ   = (bf16*)(ws + 16777472);   // [4096,1536] — dead after q-GEMM; reused as P3/P4
    bf16* cKV  = (bf16*)(ws + 29360384);   // [4096, 512]
    bf16* kpeb = (bf16*)(ws + 33554688);   // [4096,  64]
    bf16* qnop = (bf16*)(ws + 34078976);   // [4096,2048]
    bf16* qpeb = (bf16*)(ws + 50856192);   // [4096,1024]
    bf16* kvb  = (bf16*)(ws + 59244800);   // [4096,4096] — written late; holds P1/P2 early
    bf16* yb   = (bf16*)(ws + 92799232);   // [4096,2048]  (end 109,576,448)

    // weight arenas (lifetime-safe overlays):
    bf16* P1 = kvb;                            // [2176][2048] x-weights^T (8.9 MB)
    bf16* P2 = (bf16*)((char*)kvb + 8912896);  // [3072][1536] q-weights^T (9.4 MB)
    bf16* P3 = cQ;                             // [4096][512]  Wkv_up^T    (4.2 MB)
    bf16* P4 = (bf16*)((char*)cQ + 4194304);   // [2048][2048] Wo^T        (8.4 MB)
    bf16* vT = xb;                             // [B*H][128][2048] V^T

    const dim3 blk(256);

    detect_kernel<<<1, dim3(64), 0, stream>>>((const unsigned short*)x, flag);
    convert_kernel<<<(B_*T_*C_)/(256*8), blk, 0, stream>>>(x, xb, B_*T_*C_, flag);

    // ---- batched transpose #1: x-path + q-path weights ----
    {
        TBatch tb;
        tb.d[0] = { Wq_down,  P1,               C_,  QLR_,     0, QLR_/32 };    // 3072 blks
        tb.d[1] = { Wkv_down, P1 + 1536*2048,   C_,  KLR_,  3072, KLR_/32 };    // 1024
        tb.d[2] = { Wk_pe,    P1 + 2048*2048,   C_,  RD_,   4096, RD_/32  };    //  128
        tb.d[3] = { Wq_up,    P2,               QLR_, 2048, 4224, 2048/32 };    // 3072
        tb.d[4] = { Wq_pe,    P2 + 2048*1536,   QLR_, 1024, 7296, 1024/32 };    // 1536
        tb.nseg = 5;
        transpose_batch<<<8832, blk, 0, stream>>>(tb, flag);
    }

    // ---- fused x-projection GEMM: x @ [Wq_down | Wkv_down | Wk_pe] ----
    {
        GOuts go; go.nseg = 3;
        go.p[0]=cQ;   go.start[0]=0;    go.stride[0]=QLR_;
        go.p[1]=cKV;  go.start[1]=1536; go.stride[1]=KLR_;
        go.p[2]=kpeb; go.start[2]=2048; go.stride[2]=RD_;
        mfma_gemm<<<dim3(17, 32), blk, 0, stream>>>(xb, P1, go, 2112, C_, flag, 0);
    }
    rms_kernel<6><<<B_*T_, blk, 0, stream>>>(cQ, q_norm_w, flag);
    rms_kernel<2><<<B_*T_, blk, 0, stream>>>(cKV, kv_norm_w, flag);
    kpe_rms_rope<<<B_*T_, dim3(64), 0, stream>>>(kpeb, kpe_nw, flag);

    // ---- fused q-projection GEMM: cQ @ [Wq_up | Wq_pe] ----
    {
        GOuts go; go.nseg = 2;
        go.p[0]=qnop; go.start[0]=0;    go.stride[0]=H_*HD_;
        go.p[1]=qpeb; go.start[1]=2048; go.stride[1]=H_*RD_;
        go.p[2]=nullptr; go.start[2]=0; go.stride[2]=0;
        mfma_gemm<<<dim3(24, 32), blk, 0, stream>>>(cQ, P2, go, 3072, QLR_, flag, 0);
    }
    qpe_rope<<<B_*T_, blk, 0, stream>>>(qpeb);

    // ---- batched transpose #2: Wkv_up, Wo (cQ now dead) ----
    {
        TBatch tb;
        tb.d[0] = { Wkv_up, P3, KLR_, H_*2*HD_,    0, (H_*2*HD_)/32 };  // 2048 blks
        tb.d[1] = { Wo,     P4, H_*HD_, C_,     2048, C_/32 };          // 4096
        tb.d[2] = tb.d[1]; tb.d[3] = tb.d[1]; tb.d[4] = tb.d[1];
        tb.nseg = 2;
        transpose_batch<<<6144, blk, 0, stream>>>(tb, flag);
    }

    // ---- kv up-projection, then V transpose (xb dead) ----
    {
        GOuts go; go.nseg = 1;
        go.p[0]=kvb; go.start[0]=0; go.stride[0]=H_*2*HD_;
        go.p[1]=nullptr; go.start[1]=0; go.stride[1]=0;
        go.p[2]=nullptr; go.start[2]=0; go.stride[2]=0;
        mfma_gemm<<<dim3(32, 32), blk, 0, stream>>>(cKV, P3, go, H_*2*HD_, KLR_, flag, 0);
    }
    transpose_v_kernel<<<dim3((H_*HD_)/32, (B_*T_)/32), blk, 0, stream>>>(kvb, vT);

    // ---- attention ----
    flash_attn<<<dim3(H_, T_/64, B_), blk, 0, stream>>>(qnop, qpeb, kvb, kpeb, vT, yb);

    // ---- output projection (dtype of d_out per flag) ----
    {
        GOuts go; go.nseg = 1;
        go.p[0]=d_out; go.start[0]=0; go.stride[0]=C_;
        go.p[1]=nullptr; go.start[1]=0; go.stride[1]=0;
        go.p[2]=nullptr; go.start[2]=0; go.stride[2]=0;
        mfma_gemm<<<dim3(C_/128, 32), blk, 0, stream>>>(yb, P4, go, C_, H_*HD_, flag, 1);
    }
}

// Round 8
// 477.592 us; speedup vs baseline: 1.4672x; 1.4672x over previous
//
#include <hip/hip_runtime.h>
#include <hip/hip_bf16.h>
#include <cmath>

typedef __hip_bfloat16 bf16;
typedef __attribute__((ext_vector_type(8))) short s16x8;
typedef __attribute__((ext_vector_type(4))) float f32x4;

#define B_   2
#define T_   2048
#define C_   2048
#define H_   16
#define HD_  128
#define RD_  64
#define QLR_ 1536
#define KLR_ 512
#define SCALE_ 0.07216878364870322f   // (128+64)^-0.5

static __device__ __forceinline__ float b2f(bf16 v){ return __bfloat162float(v); }
static __device__ __forceinline__ bf16  f2b(float v){ return __float2bfloat16(v); }
static __device__ __forceinline__ float us2f(unsigned short u){
    union { unsigned short s[2]; float f; } v; v.s[0]=0; v.s[1]=u; return v.f;
}
static __device__ __forceinline__ float ldS(const void* p, size_t i, int isf32){
    return isf32 ? ((const float*)p)[i] : b2f(((const bf16*)p)[i]);
}
static __device__ __forceinline__ void ld4(const void* p, size_t i, int isf32, float* o){
    if (isf32) {
        float4 v = *(const float4*)((const float*)p + i);
        o[0]=v.x; o[1]=v.y; o[2]=v.z; o[3]=v.w;
    } else {
        ushort4 u = *(const ushort4*)((const bf16*)p + i);
        o[0]=us2f(u.x); o[1]=us2f(u.y); o[2]=us2f(u.z); o[3]=us2f(u.w);
    }
}

// ---------------------------------------------------------------------------
// dtype detector (1 = harness buffers are f32, 0 = bf16)
// ---------------------------------------------------------------------------
__global__ __launch_bounds__(64) void detect_kernel(const unsigned short* __restrict__ x,
                                                    int* __restrict__ flag)
{
    int big = 0;
    for (int i = threadIdx.x; i < 1024; i += 64) {
        const unsigned short u = x[2*i];
        const int e = (u >> 7) & 0xFF;
        if (e >= 139) big++;
    }
    #pragma unroll
    for (int off = 32; off; off >>= 1) big += __shfl_down(big, off, 64);
    if (threadIdx.x == 0) *flag = (big > 8) ? 1 : 0;
}

// ---------------------------------------------------------------------------
// Elementwise convert harness buffer -> bf16 (8 elems/thread)
// ---------------------------------------------------------------------------
__global__ __launch_bounds__(256) void convert_kernel(const void* __restrict__ in,
                                                      bf16* __restrict__ out, int n,
                                                      const int* __restrict__ flag)
{
    const int f = *flag;
    const int i0 = (blockIdx.x * 256 + threadIdx.x) * 8;
    if (i0 >= n) return;
    float v[8];
    ld4(in, i0, f, v);
    ld4(in, i0 + 4, f, v + 4);
    bf16* o = out + i0;
    #pragma unroll
    for (int k = 0; k < 8; ++k) o[k] = f2b(v[k]);
}

// ---------------------------------------------------------------------------
// Batched transpose: several harness weights [R][Cc] -> bf16 [Cc][R].
// ---------------------------------------------------------------------------
struct TDesc { const void* in; bf16* out; int R, Cc, blkStart, nx; };
struct TBatch { TDesc d[5]; int nseg; };

__global__ __launch_bounds__(256) void transpose_batch(TBatch tb,
                                                       const int* __restrict__ flag)
{
    const int f = *flag;
    const int bid = blockIdx.x;
    int s = 0;
    #pragma unroll
    for (int i = 1; i < 5; ++i)
        if (i < tb.nseg && bid >= tb.d[i].blkStart) s = i;
    const TDesc d = tb.d[s];
    const int local = bid - d.blkStart;
    const int c0 = (local % d.nx) * 32;
    const int r0 = (local / d.nx) * 32;

    __shared__ float tile[32][33];
    const int tx = threadIdx.x & 31, ty = threadIdx.x >> 5;  // 32 x 8
    #pragma unroll
    for (int i = 0; i < 4; ++i)
        tile[ty + 8*i][tx] = ldS(d.in, (size_t)(r0 + ty + 8*i) * d.Cc + c0 + tx, f);
    __syncthreads();
    #pragma unroll
    for (int i = 0; i < 4; ++i)
        d.out[(size_t)(c0 + ty + 8*i) * d.R + r0 + tx] = f2b(tile[tx][ty + 8*i]);
}

// ---------------------------------------------------------------------------
// Transpose V half of kv [4096][4096] into vT[(b*H+h)*HD + d][t].
// ---------------------------------------------------------------------------
__global__ __launch_bounds__(256) void transpose_v_kernel(const bf16* __restrict__ kvb,
                                                          bf16* __restrict__ vT)
{
    __shared__ bf16 tile[32][34];
    const int c0 = blockIdx.x * 32;        // v-col 0..2047
    const int r0 = blockIdx.y * 32;        // row 0..4095 (b*T + t)
    const int tx = threadIdx.x & 31, ty = threadIdx.x >> 5;
    #pragma unroll
    for (int i = 0; i < 4; ++i)
        tile[ty + 8*i][tx] = kvb[(size_t)(r0 + ty + 8*i) * (H_*256) + H_*128 + c0 + tx];
    __syncthreads();
    const int b  = r0 >> 11;
    const int t0 = r0 & (T_ - 1);
    #pragma unroll
    for (int i = 0; i < 4; ++i) {
        const int c  = c0 + ty + 8*i;
        const int hh = c >> 7, dd = c & 127;
        vT[(((size_t)b*H_ + hh)*HD_ + dd)*T_ + t0 + tx] = tile[tx][ty + 8*i];
    }
}

struct GOuts { void* p[3]; int start[3]; int stride[3]; int nseg; };

// ---------------------------------------------------------------------------
// mfma_gemm v5: 128x128 tile, BK=64, REGISTER-STAGED dbuf — NAMED scalars.
// C[M,N] = A[M,K] @ BT[N,K]^T.  M%128==0, K%128==0 (nkt even), N via ccol<N
// guard; segment starts multiples of 128.
//
// Round-8 fix of round-7: the uint4 rg0[8]/rg1[8] ARRAYS went to scratch
// (VGPR=88, WRITE_SIZE=228MB, MfmaUtil<10%) — SROA runs before loop
// unrolling, so loop-indexed allocas are never promoted (rule #20).
// flash_attn's PF macro works because it uses NAMED scalars. Same here:
// 16 individually named uint4 (xa0..xa3,xb0..xb3 / ya0..ya3,yb0..yb3).
// Pipeline (per iteration, 2 K-tiles, 1 lgkm-only barrier per tile):
//   GLD(y, t+2) | DSW(buf1<-x tile t+1) | CMP(buf0 tile t) | LBAR
//   GLD(x, t+3) | DSW(buf0<-y tile t+2) | CMP(buf1 tile t+1) | LBAR
// The wait before each DSW is a COUNTED, value-dependent vmcnt emitted by
// the compiler (the 8 newer loads stay in flight); barriers are
// lgkmcnt(0)+s_barrier only — vmcnt is never drained to 0 in the loop.
// WAR safety: CMP(buf)'s ds_reads complete before the LBAR that precedes
// the next DSW into the same buf. VGPR ~190 @ (256,2): no spill headroom
// issue. LDS 2x32KB -> 2 blocks/CU.
// LDS XOR slot-swizzle (verified conflict-free r4-r6):
//   write: linear dest tid*16; global source 16B-col = (tid&7)^((tid>>3)&7)
//   read:  physical slot = (ks*4+quad) ^ (l16&7)
// ---------------------------------------------------------------------------
__global__ __launch_bounds__(256, 2) void mfma_gemm(const bf16* __restrict__ A,
                                                    const bf16* __restrict__ BT,
                                                    GOuts go, int N, int K,
                                                    const int* __restrict__ flag, int cH)
{
    __shared__ __align__(16) char smem[65536];
    const int cf   = cH ? *flag : 0;
    const int tid  = threadIdx.x;
    const int lane = tid & 63;
    const int quad = lane >> 4;
    const int l16  = lane & 15;
    const int w    = tid >> 6;
    const int wm   = w >> 1, wn = w & 1;
    const int bm   = blockIdx.y * 128, bn = blockIdx.x * 128;

    int seg = 0;
    #pragma unroll
    for (int i = 1; i < 3; ++i)
        if (i < go.nseg && bn >= go.start[i]) seg = i;
    void* const dstp   = go.p[seg];
    const int  dstoff  = go.start[seg];
    const int  dstride = go.stride[seg];

    const int nkt = K >> 6;                       // K-tiles of 64; even for all uses

    // staging: linear LDS dest, inverse-swizzled global source (rule 21)
    const int sR   = tid >> 3;                    // row 0..31 within 32-row group
    const int sCol = ((tid & 7) ^ (sR & 7)) * 8;  // bf16 col: slot ^ (row&7)
    const bf16* gA = A  + (size_t)(bm + sR) * K + sCol;
    const bf16* gB = BT + (size_t)(bn + sR) * K + sCol;
    // ds_read swizzle key = row&7 = l16&7 (rows are i*16+l16, 16==0 mod 8)
    const int rxk  = l16 & 7;
    const int aOff = (wm*64 + l16) * 128;
    const int bOff = 16384 + (wn*64 + l16) * 128;

    f32x4 acc[4][4];
    #pragma unroll
    for (int i = 0; i < 4; ++i)
        #pragma unroll
        for (int j = 0; j < 4; ++j)
            acc[i][j] = (f32x4){0.f, 0.f, 0.f, 0.f};

    // 16 NAMED staging registers (rule #20: no arrays)
    uint4 xa0, xa1, xa2, xa3, xb0, xb1, xb2, xb3;
    uint4 ya0, ya1, ya2, ya3, yb0, yb1, yb2, yb3;

    #define GLD(a0,a1,a2,a3,b0,b1,b2,b3, kt) do {                                \
        const int ke_ = ((kt) < nkt ? (kt) : nkt-1) * 64;                        \
        a0 = *(const uint4*)(gA + (size_t)( 0) * K + ke_);                       \
        a1 = *(const uint4*)(gA + (size_t)(32) * K + ke_);                       \
        a2 = *(const uint4*)(gA + (size_t)(64) * K + ke_);                       \
        a3 = *(const uint4*)(gA + (size_t)(96) * K + ke_);                       \
        b0 = *(const uint4*)(gB + (size_t)( 0) * K + ke_);                       \
        b1 = *(const uint4*)(gB + (size_t)(32) * K + ke_);                       \
        b2 = *(const uint4*)(gB + (size_t)(64) * K + ke_);                       \
        b3 = *(const uint4*)(gB + (size_t)(96) * K + ke_);                       \
    } while (0)

    #define DSW(buf, a0,a1,a2,a3,b0,b1,b2,b3) do {                               \
        *(uint4*)(smem + (buf)*32768 +         0 + tid*16) = a0;                 \
        *(uint4*)(smem + (buf)*32768 +      4096 + tid*16) = a1;                 \
        *(uint4*)(smem + (buf)*32768 +      8192 + tid*16) = a2;                 \
        *(uint4*)(smem + (buf)*32768 +     12288 + tid*16) = a3;                 \
        *(uint4*)(smem + (buf)*32768 + 16384 +     0 + tid*16) = b0;             \
        *(uint4*)(smem + (buf)*32768 + 16384 +  4096 + tid*16) = b1;             \
        *(uint4*)(smem + (buf)*32768 + 16384 +  8192 + tid*16) = b2;             \
        *(uint4*)(smem + (buf)*32768 + 16384 + 12288 + tid*16) = b3;             \
    } while (0)

    #define CMP(buf) do {                                                        \
        __builtin_amdgcn_s_setprio(1);                                           \
        _Pragma("unroll")                                                        \
        for (int ks_ = 0; ks_ < 2; ++ks_) {                                      \
            s16x8 af0_ = *(const s16x8*)(smem + (buf)*32768 + aOff + 0*2048      \
                          + ((((ks_<<2)|quad) ^ rxk) << 4));                     \
            s16x8 af1_ = *(const s16x8*)(smem + (buf)*32768 + aOff + 1*2048      \
                          + ((((ks_<<2)|quad) ^ rxk) << 4));                     \
            s16x8 af2_ = *(const s16x8*)(smem + (buf)*32768 + aOff + 2*2048      \
                          + ((((ks_<<2)|quad) ^ rxk) << 4));                     \
            s16x8 af3_ = *(const s16x8*)(smem + (buf)*32768 + aOff + 3*2048      \
                          + ((((ks_<<2)|quad) ^ rxk) << 4));                     \
            _Pragma("unroll")                                                    \
            for (int j_ = 0; j_ < 4; ++j_) {                                     \
                const s16x8 bf_ = *(const s16x8*)(smem + (buf)*32768 + bOff      \
                          + j_*2048 + ((((ks_<<2)|quad) ^ rxk) << 4));           \
                acc[0][j_] = __builtin_amdgcn_mfma_f32_16x16x32_bf16(            \
                    af0_, bf_, acc[0][j_], 0, 0, 0);                             \
                acc[1][j_] = __builtin_amdgcn_mfma_f32_16x16x32_bf16(            \
                    af1_, bf_, acc[1][j_], 0, 0, 0);                             \
                acc[2][j_] = __builtin_amdgcn_mfma_f32_16x16x32_bf16(            \
                    af2_, bf_, acc[2][j_], 0, 0, 0);                             \
                acc[3][j_] = __builtin_amdgcn_mfma_f32_16x16x32_bf16(            \
                    af3_, bf_, acc[3][j_], 0, 0, 0);                             \
            }                                                                    \
        }                                                                        \
        __builtin_amdgcn_s_setprio(0);                                           \
    } while (0)

    // lgkm-only barrier: does NOT drain vmcnt -> staged loads stay in flight.
    #define LBAR asm volatile("s_waitcnt lgkmcnt(0)\n\ts_barrier" ::: "memory")

    // prologue: tile0 -> buf0; tile1 -> x-regs
    GLD(xa0,xa1,xa2,xa3,xb0,xb1,xb2,xb3, 0);
    DSW(0, xa0,xa1,xa2,xa3,xb0,xb1,xb2,xb3);
    GLD(xa0,xa1,xa2,xa3,xb0,xb1,xb2,xb3, 1);
    LBAR;

    const int nit = nkt >> 1;
    for (int i = 0; i < nit; ++i) {
        const int t = 2*i;
        // half A: compute tile t (buf0); publish tile t+1; fetch tile t+2
        GLD(ya0,ya1,ya2,ya3,yb0,yb1,yb2,yb3, t+2);
        DSW(1, xa0,xa1,xa2,xa3,xb0,xb1,xb2,xb3);   // counted vmcnt (y in flight)
        CMP(0);
        LBAR;
        // half B: compute tile t+1 (buf1); publish tile t+2; fetch tile t+3
        GLD(xa0,xa1,xa2,xa3,xb0,xb1,xb2,xb3, t+3);
        DSW(0, ya0,ya1,ya2,ya3,yb0,yb1,yb2,yb3);
        CMP(1);
        LBAR;
    }

    #undef GLD
    #undef DSW
    #undef CMP
    #undef LBAR

    #pragma unroll
    for (int i = 0; i < 4; ++i) {
        const int crow = bm + wm*64 + i*16 + quad*4;
        #pragma unroll
        for (int r = 0; r < 4; ++r) {
            #pragma unroll
            for (int j = 0; j < 4; ++j) {
                const int ccol = bn + wn*64 + j*16 + l16;
                if (ccol < N) {
                    const size_t idx = (size_t)(crow + r) * dstride + (ccol - dstoff);
                    if (cf) ((float*)dstp)[idx] = acc[i][j][r];
                    else    ((bf16*)dstp)[idx] = f2b(acc[i][j][r]);
                }
            }
        }
    }
}

// ---------------------------------------------------------------------------
// In-place RMSNorm over rows of X [rows, NPER*256] (internal bf16)
// ---------------------------------------------------------------------------
template<int NPER>
__global__ __launch_bounds__(256) void rms_kernel(bf16* __restrict__ X,
                                                  const void* __restrict__ w,
                                                  const int* __restrict__ flag)
{
    const int wf = *flag;
    const int ncols = NPER * 256;
    __shared__ float red[4];
    const int row = blockIdx.x;
    const int tid = threadIdx.x;
    bf16* xr = X + (size_t)row * ncols;
    float vals[NPER];
    float ss = 0.f;
    #pragma unroll
    for (int i = 0; i < NPER; ++i) {
        float v = b2f(xr[tid + i*256]);
        vals[i] = v; ss += v*v;
    }
    #pragma unroll
    for (int off = 32; off; off >>= 1) ss += __shfl_down(ss, off, 64);
    if ((tid & 63) == 0) red[tid >> 6] = ss;
    __syncthreads();
    const float tot = red[0]+red[1]+red[2]+red[3];
    const float rs  = rsqrtf(tot / (float)ncols + 1e-6f);
    #pragma unroll
    for (int i = 0; i < NPER; ++i) {
        const int c = tid + i*256;
        xr[c] = f2b(vals[i] * rs * ldS(w, c, wf));
    }
}

// ---------------------------------------------------------------------------
// k_pe: in-place RMSNorm over 64 cols + RoPE
// ---------------------------------------------------------------------------
__global__ __launch_bounds__(64) void kpe_rms_rope(bf16* __restrict__ X,
                                                   const void* __restrict__ w,
                                                   const int* __restrict__ flag)
{
    const int wf   = *flag;
    const int row  = blockIdx.x;
    const int t    = row & (T_ - 1);
    const int lane = threadIdx.x;
    bf16* xr = X + (size_t)row * RD_;
    const float v = b2f(xr[lane]);
    float ss = v * v;
    #pragma unroll
    for (int off = 32; off; off >>= 1) ss += __shfl_down(ss, off, 64);
    ss = __shfl(ss, 0, 64);
    const float rs = rsqrtf(ss / 64.f + 1e-6f);
    const float xn = v * rs * ldS(w, lane, wf);
    const int   i  = lane & 31;
    const float freq = powf(10000.f, -(float)(2*i) / 64.f);
    const float ang  = (float)t * freq;
    const float s = sinf(ang), c = cosf(ang);
    const float other = __shfl_xor(xn, 32, 64);
    const float o = (lane < 32) ? (xn * c - other * s) : (other * s + xn * c);
    xr[lane] = f2b(o);
}

// ---------------------------------------------------------------------------
// q_pe RoPE in-place: X [B*T, H*64]
// ---------------------------------------------------------------------------
__global__ __launch_bounds__(256) void qpe_rope(bf16* __restrict__ X)
{
    const int row = blockIdx.x;
    const int t   = row & (T_ - 1);
    bf16* xr = X + (size_t)row * (H_ * RD_);
    const int tid = threadIdx.x;
    #pragma unroll
    for (int pp = 0; pp < 2; ++pp) {
        const int p  = tid + pp * 256;
        const int hh = p >> 5;
        const int i  = p & 31;
        const int i0 = hh * 64 + i;
        const int i1 = i0 + 32;
        const float x1 = b2f(xr[i0]), x2 = b2f(xr[i1]);
        const float freq = powf(10000.f, -(float)(2*i) / 64.f);
        const float ang  = (float)t * freq;
        const float s = sinf(ang), c = cosf(ang);
        xr[i0] = f2b(x1 * c - x2 * s);
        xr[i1] = f2b(x1 * s + x2 * c);
    }
}

// ---------------------------------------------------------------------------
// Flash-style MFMA attention v5 (passing @112.5us, rounds 2-7 verified):
// tight LDS + XOR swizzle (48KB, 3 blocks/CU), spill-free softmax.
// ---------------------------------------------------------------------------
__global__ __launch_bounds__(256, 2) void flash_attn(const bf16* __restrict__ qnop,
                                                     const bf16* __restrict__ qpe,
                                                     const bf16* __restrict__ kv,
                                                     const bf16* __restrict__ kpe,
                                                     const bf16* __restrict__ vT,
                                                     bf16* __restrict__ y)
{
    __shared__ __align__(16) short Klds[64 * 192];
    __shared__ __align__(16) short Vt[128 * 64];
    __shared__ __align__(16) short Plds[4][16 * 64];

    const int h   = blockIdx.x;
    const int qt  = 31 - (int)blockIdx.y;          // heavy blocks dispatched first
    const int b   = blockIdx.z;
    const int q0  = qt * 64;
    const int tid = threadIdx.x;
    const int w    = tid >> 6;
    const int lane = tid & 63;
    const int quad = lane >> 4;
    const int l16  = lane & 15;
    const int rk   = l16 & 7;
    const int rkp  = (l16 ^ (l16 >> 3)) & 7;
    const int row0 = q0 + w * 16;
    const size_t bT = (size_t)b * T_;
    const int bh  = b * H_ + h;

    const int kR = tid >> 4, kS = tid & 15;
    const int pR = tid >> 3, pS = tid & 7;
    const int vD = tid >> 3, vS = tid & 7;

    const bf16* gK = kv  + (bT + kR) * (H_*256) + h*128 + kS*8;
    const bf16* gP = kpe + (bT + pR) * RD_ + pS*8;
    const bf16* gV = vT  + ((size_t)bh*HD_ + vD) * T_ + vS*8;

    short* const wK = &Klds[kR*192 + ((kS ^ (kR & 7)) << 3)];
    short* const wP = &Klds[pR*192 + 128 + ((pS ^ (pR & 7)) << 3)];
    short* const wV = &Vt[vD*64 + ((vS ^ (vD & 7)) << 3)];

    s16x8 aq[6];
    {
        const size_t r = bT + row0 + l16;
        const bf16* qn = qnop + r * (H_*128) + h*128 + quad*8;
        #pragma unroll
        for (int kk = 0; kk < 4; ++kk) aq[kk] = *(const s16x8*)(qn + kk*32);
        const bf16* qp = qpe + r * (H_*64) + h*64 + quad*8;
        aq[4] = *(const s16x8*)(qp);
        aq[5] = *(const s16x8*)(qp + 32);
    }

    f32x4 o[8];
    #pragma unroll
    for (int i = 0; i < 8; ++i) o[i] = (f32x4){0.f,0.f,0.f,0.f};
    float m_run[4] = {-1e30f,-1e30f,-1e30f,-1e30f};
    float l_run[4] = {0.f,0.f,0.f,0.f};

    uint4 k0, k1, k2, k3, p0, p1, v0, v1, v2, v3;
    #define PF(J0) do {                                                     \
        const bf16* a_ = gK + (size_t)(J0) * (H_*256);                      \
        k0 = *(const uint4*)(a_);                                           \
        k1 = *(const uint4*)(a_ + 16*(H_*256));                             \
        k2 = *(const uint4*)(a_ + 32*(H_*256));                             \
        k3 = *(const uint4*)(a_ + 48*(H_*256));                             \
        const bf16* p_ = gP + (size_t)(J0) * RD_;                           \
        p0 = *(const uint4*)(p_);                                           \
        p1 = *(const uint4*)(p_ + 32*RD_);                                  \
        const bf16* v_ = gV + (J0);                                         \
        v0 = *(const uint4*)(v_);                                           \
        v1 = *(const uint4*)(v_ + 32*T_);                                   \
        v2 = *(const uint4*)(v_ + 64*T_);                                   \
        v3 = *(const uint4*)(v_ + 96*T_);                                   \
    } while (0)

    PF(0);

    const int ntiles = qt + 1;
    for (int it = 0; it < ntiles; ++it) {
        const int j0 = it * 64;
        asm volatile("s_waitcnt lgkmcnt(0)\n\ts_barrier" ::: "memory");

        *(uint4*)(wK)          = k0;
        *(uint4*)(wK + 16*192) = k1;
        *(uint4*)(wK + 32*192) = k2;
        *(uint4*)(wK + 48*192) = k3;
        *(uint4*)(wP)          = p0;
        *(uint4*)(wP + 32*192) = p1;
        *(uint4*)(wV)          = v0;
        *(uint4*)(wV + 32*64)  = v1;
        *(uint4*)(wV + 64*64)  = v2;
        *(uint4*)(wV + 96*64)  = v3;

        if (it + 1 < ntiles) PF(j0 + 64);

        asm volatile("s_waitcnt lgkmcnt(0)\n\ts_barrier" ::: "memory");

        if (j0 <= row0 + 15) {
            const bool needmask = (j0 + 63 > row0);
            f32x4 s[4];
            #pragma unroll
            for (int nsub = 0; nsub < 4; ++nsub) {
                f32x4 acc = (f32x4){0.f,0.f,0.f,0.f};
                #pragma unroll
                for (int kk = 0; kk < 6; ++kk) {
                    const s16x8 bk = *(const s16x8*)&Klds[(nsub*16 + l16)*192
                                        + ((((kk << 2) | quad) ^ rk) << 3)];
                    acc = __builtin_amdgcn_mfma_f32_16x16x32_bf16(aq[kk], bk, acc, 0, 0, 0);
                }
                #pragma unroll
                for (int reg = 0; reg < 4; ++reg) acc[reg] *= SCALE_;
                s[nsub] = acc;
            }
            if (needmask) {
                #pragma unroll
                for (int nsub = 0; nsub < 4; ++nsub)
                    #pragma unroll
                    for (int reg = 0; reg < 4; ++reg) {
                        const int col = j0 + nsub*16 + l16;
                        const int row = row0 + quad*4 + reg;
                        if (col > row) s[nsub][reg] = -1e30f;
                    }
            }
            float mt[4], alpha[4], rs[4];
            #pragma unroll
            for (int reg = 0; reg < 4; ++reg)
                mt[reg] = fmaxf(fmaxf(s[0][reg], s[1][reg]), fmaxf(s[2][reg], s[3][reg]));
            #pragma unroll
            for (int d = 1; d < 16; d <<= 1)
                #pragma unroll
                for (int reg = 0; reg < 4; ++reg)
                    mt[reg] = fmaxf(mt[reg], __shfl_xor(mt[reg], d, 64));
            #pragma unroll
            for (int reg = 0; reg < 4; ++reg) {
                const float mnew = fmaxf(m_run[reg], mt[reg]);
                alpha[reg] = __expf(m_run[reg] - mnew);
                m_run[reg] = mnew;
                rs[reg] = 0.f;
            }
            #pragma unroll
            for (int nsub = 0; nsub < 4; ++nsub)
                #pragma unroll
                for (int reg = 0; reg < 4; ++reg) {
                    const float p = __expf(s[nsub][reg] - m_run[reg]);
                    s[nsub][reg] = p;
                    rs[reg] += p;
                }
            #pragma unroll
            for (int d = 1; d < 16; d <<= 1)
                #pragma unroll
                for (int reg = 0; reg < 4; ++reg)
                    rs[reg] += __shfl_xor(rs[reg], d, 64);
            #pragma unroll
            for (int reg = 0; reg < 4; ++reg)
                l_run[reg] = l_run[reg] * alpha[reg] + rs[reg];

            #pragma unroll
            for (int nsub = 0; nsub < 4; ++nsub)
                #pragma unroll
                for (int reg = 0; reg < 4; ++reg) {
                    const bf16 pv = f2b(s[nsub][reg]);
                    const int prow = (quad << 2) + reg;
                    const int pk   = (prow ^ (prow >> 3)) & 7;
                    const int pby  = ((nsub << 5) + (l16 << 1)) ^ (pk << 4);
                    Plds[w][prow*64 + (pby >> 1)] = *(const short*)&pv;
                }
            #pragma unroll
            for (int n2 = 0; n2 < 8; ++n2)
                #pragma unroll
                for (int reg = 0; reg < 4; ++reg)
                    o[n2][reg] *= alpha[reg];

            const s16x8 ap0 = *(const s16x8*)&Plds[w][l16*64 + (((quad    ) ^ rkp) << 3)];
            const s16x8 ap1 = *(const s16x8*)&Plds[w][l16*64 + (((quad | 4) ^ rkp) << 3)];
            #pragma unroll
            for (int n2 = 0; n2 < 8; ++n2) {
                const s16x8 bv0 = *(const s16x8*)&Vt[(n2*16 + l16)*64 + (((quad    ) ^ rk) << 3)];
                const s16x8 bv1 = *(const s16x8*)&Vt[(n2*16 + l16)*64 + (((quad | 4) ^ rk) << 3)];
                o[n2] = __builtin_amdgcn_mfma_f32_16x16x32_bf16(ap0, bv0, o[n2], 0, 0, 0);
                o[n2] = __builtin_amdgcn_mfma_f32_16x16x32_bf16(ap1, bv1, o[n2], 0, 0, 0);
            }
        }
    }
    #undef PF

    #pragma unroll
    for (int reg = 0; reg < 4; ++reg) {
        const float inv = 1.f / l_run[reg];
        const size_t r = bT + row0 + quad*4 + reg;
        bf16* yr = y + r * (H_*128) + h*128 + l16;
        #pragma unroll
        for (int n2 = 0; n2 < 8; ++n2)
            yr[n2*16] = f2b(o[n2][reg] * inv);
    }
}

// ---------------------------------------------------------------------------
extern "C" void kernel_launch(void* const* d_in, const int* in_sizes, int n_in,
                              void* d_out, int out_size, void* d_ws, size_t ws_size,
                              hipStream_t stream)
{
    const void* x         = d_in[0];
    const void* Wq_down   = d_in[1];
    const void* q_norm_w  = d_in[2];
    const void* Wq_up     = d_in[3];
    const void* Wq_pe     = d_in[4];
    const void* Wkv_down  = d_in[5];
    const void* kv_norm_w = d_in[6];
    const void* Wkv_up    = d_in[7];
    const void* Wk_pe     = d_in[8];
    const void* kpe_nw    = d_in[9];
    const void* Wo        = d_in[10];

    char* ws = (char*)d_ws;
    int*  flag = (int*)(ws + 0);
    bf16* xb   = (bf16*)(ws + 256);        // [4096,2048] — dead after x-GEMM; reused as vT
    bf16* cQ   = (bf16*)(ws + 16777472);   // [4096,1536] — dead after q-GEMM; reused as P3/P4
    bf16* cKV  = (bf16*)(ws + 29360384);   // [4096, 512]
    bf16* kpeb = (bf16*)(ws + 33554688);   // [4096,  64]
    bf16* qnop = (bf16*)(ws + 34078976);   // [4096,2048]
    bf16* qpeb = (bf16*)(ws + 50856192);   // [4096,1024]
    bf16* kvb  = (bf16*)(ws + 59244800);   // [4096,4096] — written late; holds P1/P2 early
    bf16* yb   = (bf16*)(ws + 92799232);   // [4096,2048]  (end 109,576,448)

    // weight arenas (lifetime-safe overlays):
    bf16* P1 = kvb;                            // [2176][2048] x-weights^T (8.9 MB)
    bf16* P2 = (bf16*)((char*)kvb + 8912896);  // [3072][1536] q-weights^T (9.4 MB)
    bf16* P3 = cQ;                             // [4096][512]  Wkv_up^T    (4.2 MB)
    bf16* P4 = (bf16*)((char*)cQ + 4194304);   // [2048][2048] Wo^T        (8.4 MB)
    bf16* vT = xb;                             // [B*H][128][2048] V^T

    const dim3 blk(256);

    detect_kernel<<<1, dim3(64), 0, stream>>>((const unsigned short*)x, flag);
    convert_kernel<<<(B_*T_*C_)/(256*8), blk, 0, stream>>>(x, xb, B_*T_*C_, flag);

    // ---- batched transpose #1: x-path + q-path weights ----
    {
        TBatch tb;
        tb.d[0] = { Wq_down,  P1,               C_,  QLR_,     0, QLR_/32 };    // 3072 blks
        tb.d[1] = { Wkv_down, P1 + 1536*2048,   C_,  KLR_,  3072, KLR_/32 };    // 1024
        tb.d[2] = { Wk_pe,    P1 + 2048*2048,   C_,  RD_,   4096, RD_/32  };    //  128
        tb.d[3] = { Wq_up,    P2,               QLR_, 2048, 4224, 2048/32 };    // 3072
        tb.d[4] = { Wq_pe,    P2 + 2048*1536,   QLR_, 1024, 7296, 1024/32 };    // 1536
        tb.nseg = 5;
        transpose_batch<<<8832, blk, 0, stream>>>(tb, flag);
    }

    // ---- fused x-projection GEMM: x @ [Wq_down | Wkv_down | Wk_pe] ----
    {
        GOuts go; go.nseg = 3;
        go.p[0]=cQ;   go.start[0]=0;    go.stride[0]=QLR_;
        go.p[1]=cKV;  go.start[1]=1536; go.stride[1]=KLR_;
        go.p[2]=kpeb; go.start[2]=2048; go.stride[2]=RD_;
        mfma_gemm<<<dim3(17, 32), blk, 0, stream>>>(xb, P1, go, 2112, C_, flag, 0);
    }
    rms_kernel<6><<<B_*T_, blk, 0, stream>>>(cQ, q_norm_w, flag);
    rms_kernel<2><<<B_*T_, blk, 0, stream>>>(cKV, kv_norm_w, flag);
    kpe_rms_rope<<<B_*T_, dim3(64), 0, stream>>>(kpeb, kpe_nw, flag);

    // ---- fused q-projection GEMM: cQ @ [Wq_up | Wq_pe] ----
    {
        GOuts go; go.nseg = 2;
        go.p[0]=qnop; go.start[0]=0;    go.stride[0]=H_*HD_;
        go.p[1]=qpeb; go.start[1]=2048; go.stride[1]=H_*RD_;
        go.p[2]=nullptr; go.start[2]=0; go.stride[2]=0;
        mfma_gemm<<<dim3(24, 32), blk, 0, stream>>>(cQ, P2, go, 3072, QLR_, flag, 0);
    }
    qpe_rope<<<B_*T_, blk, 0, stream>>>(qpeb);

    // ---- batched transpose #2: Wkv_up, Wo (cQ now dead) ----
    {
        TBatch tb;
        tb.d[0] = { Wkv_up, P3, KLR_, H_*2*HD_,    0, (H_*2*HD_)/32 };  // 2048 blks
        tb.d[1] = { Wo,     P4, H_*HD_, C_,     2048, C_/32 };          // 4096
        tb.d[2] = tb.d[1]; tb.d[3] = tb.d[1]; tb.d[4] = tb.d[1];
        tb.nseg = 2;
        transpose_batch<<<6144, blk, 0, stream>>>(tb, flag);
    }

    // ---- kv up-projection, then V transpose (xb dead) ----
    {
        GOuts go; go.nseg = 1;
        go.p[0]=kvb; go.start[0]=0; go.stride[0]=H_*2*HD_;
        go.p[1]=nullptr; go.start[1]=0; go.stride[1]=0;
        go.p[2]=nullptr; go.start[2]=0; go.stride[2]=0;
        mfma_gemm<<<dim3(32, 32), blk, 0, stream>>>(cKV, P3, go, H_*2*HD_, KLR_, flag, 0);
    }
    transpose_v_kernel<<<dim3((H_*HD_)/32, (B_*T_)/32), blk, 0, stream>>>(kvb, vT);

    // ---- attention ----
    flash_attn<<<dim3(H_, T_/64, B_), blk, 0, stream>>>(qnop, qpeb, kvb, kpeb, vT, yb);

    // ---- output projection (dtype of d_out per flag) ----
    {
        GOuts go; go.nseg = 1;
        go.p[0]=d_out; go.start[0]=0; go.stride[0]=C_;
        go.p[1]=nullptr; go.start[1]=0; go.stride[1]=0;
        go.p[2]=nullptr; go.start[2]=0; go.stride[2]=0;
        mfma_gemm<<<dim3(C_/128, 32), blk, 0, stream>>>(yb, P4, go, C_, H_*HD_, flag, 1);
    }
}

// Round 9
// 449.567 us; speedup vs baseline: 1.5587x; 1.0623x over previous
//
#include <hip/hip_runtime.h>
#include <hip/hip_bf16.h>
#include <cmath>

typedef __hip_bfloat16 bf16;
typedef __attribute__((ext_vector_type(8))) short s16x8;
typedef __attribute__((ext_vector_type(4))) float f32x4;

#define B_   2
#define T_   2048
#define C_   2048
#define H_   16
#define HD_  128
#define RD_  64
#define QLR_ 1536
#define KLR_ 512
#define SCALE_ 0.07216878364870322f   // (128+64)^-0.5

static __device__ __forceinline__ float b2f(bf16 v){ return __bfloat162float(v); }
static __device__ __forceinline__ bf16  f2b(float v){ return __float2bfloat16(v); }
static __device__ __forceinline__ float us2f(unsigned short u){
    union { unsigned short s[2]; float f; } v; v.s[0]=0; v.s[1]=u; return v.f;
}
static __device__ __forceinline__ float ldS(const void* p, size_t i, int isf32){
    return isf32 ? ((const float*)p)[i] : b2f(((const bf16*)p)[i]);
}
static __device__ __forceinline__ void ld4(const void* p, size_t i, int isf32, float* o){
    if (isf32) {
        float4 v = *(const float4*)((const float*)p + i);
        o[0]=v.x; o[1]=v.y; o[2]=v.z; o[3]=v.w;
    } else {
        ushort4 u = *(const ushort4*)((const bf16*)p + i);
        o[0]=us2f(u.x); o[1]=us2f(u.y); o[2]=us2f(u.z); o[3]=us2f(u.w);
    }
}

// ---------------------------------------------------------------------------
// dtype detector (1 = harness buffers are f32, 0 = bf16)
// ---------------------------------------------------------------------------
__global__ __launch_bounds__(64) void detect_kernel(const unsigned short* __restrict__ x,
                                                    int* __restrict__ flag)
{
    int big = 0;
    for (int i = threadIdx.x; i < 1024; i += 64) {
        const unsigned short u = x[2*i];
        const int e = (u >> 7) & 0xFF;
        if (e >= 139) big++;
    }
    #pragma unroll
    for (int off = 32; off; off >>= 1) big += __shfl_down(big, off, 64);
    if (threadIdx.x == 0) *flag = (big > 8) ? 1 : 0;
}

// ---------------------------------------------------------------------------
// Elementwise convert harness buffer -> bf16 (8 elems/thread)
// ---------------------------------------------------------------------------
__global__ __launch_bounds__(256) void convert_kernel(const void* __restrict__ in,
                                                      bf16* __restrict__ out, int n,
                                                      const int* __restrict__ flag)
{
    const int f = *flag;
    const int i0 = (blockIdx.x * 256 + threadIdx.x) * 8;
    if (i0 >= n) return;
    float v[8];
    ld4(in, i0, f, v);
    ld4(in, i0 + 4, f, v + 4);
    bf16* o = out + i0;
    #pragma unroll
    for (int k = 0; k < 8; ++k) o[k] = f2b(v[k]);
}

// ---------------------------------------------------------------------------
// Batched transpose: several harness weights [R][Cc] -> bf16 [Cc][R].
// ---------------------------------------------------------------------------
struct TDesc { const void* in; bf16* out; int R, Cc, blkStart, nx; };
struct TBatch { TDesc d[5]; int nseg; };

__global__ __launch_bounds__(256) void transpose_batch(TBatch tb,
                                                       const int* __restrict__ flag)
{
    const int f = *flag;
    const int bid = blockIdx.x;
    int s = 0;
    #pragma unroll
    for (int i = 1; i < 5; ++i)
        if (i < tb.nseg && bid >= tb.d[i].blkStart) s = i;
    const TDesc d = tb.d[s];
    const int local = bid - d.blkStart;
    const int c0 = (local % d.nx) * 32;
    const int r0 = (local / d.nx) * 32;

    __shared__ float tile[32][33];
    const int tx = threadIdx.x & 31, ty = threadIdx.x >> 5;  // 32 x 8
    #pragma unroll
    for (int i = 0; i < 4; ++i)
        tile[ty + 8*i][tx] = ldS(d.in, (size_t)(r0 + ty + 8*i) * d.Cc + c0 + tx, f);
    __syncthreads();
    #pragma unroll
    for (int i = 0; i < 4; ++i)
        d.out[(size_t)(c0 + ty + 8*i) * d.R + r0 + tx] = f2b(tile[tx][ty + 8*i]);
}

// ---------------------------------------------------------------------------
// Transpose V half of kv [4096][4096] into vT[(b*H+h)*HD + d][t].
// ---------------------------------------------------------------------------
__global__ __launch_bounds__(256) void transpose_v_kernel(const bf16* __restrict__ kvb,
                                                          bf16* __restrict__ vT)
{
    __shared__ bf16 tile[32][34];
    const int c0 = blockIdx.x * 32;        // v-col 0..2047
    const int r0 = blockIdx.y * 32;        // row 0..4095 (b*T + t)
    const int tx = threadIdx.x & 31, ty = threadIdx.x >> 5;
    #pragma unroll
    for (int i = 0; i < 4; ++i)
        tile[ty + 8*i][tx] = kvb[(size_t)(r0 + ty + 8*i) * (H_*256) + H_*128 + c0 + tx];
    __syncthreads();
    const int b  = r0 >> 11;
    const int t0 = r0 & (T_ - 1);
    #pragma unroll
    for (int i = 0; i < 4; ++i) {
        const int c  = c0 + ty + 8*i;
        const int hh = c >> 7, dd = c & 127;
        vT[(((size_t)b*H_ + hh)*HD_ + dd)*T_ + t0 + tx] = tile[tx][ty + 8*i];
    }
}

struct GOuts { void* p[3]; int start[3]; int stride[3]; int nseg; };

// ---------------------------------------------------------------------------
// mfma_gemm (round-5 version, best verified @455.7us total): 128x128 tile,
// BK=64, DOUBLE-BUFFERED 2-phase schedule via global_load_lds.
// C[M,N] = A[M,K] @ BT[N,K]^T.  M%128==0, K%128==0; N via ccol<N guard;
// segment starts multiples of 128.
// Structural sweep r5-r8: gload-dbuf 455.7 / gload-single+3blk 457.5 /
// reg-staged-dbuf 477.6 -> this family plateaus here; keep the best.
//   STG(buf^1, t+1)  -> issue 8 global_load_lds (fire-and-forget)
//   LD(buf) + MFMA   -> staging overlaps a full K-tile of compute
//   vmcnt(0); barrier (once per K-tile)
// LDS 2 x 32KB = 64KB -> 2 blocks/CU. XOR slot-swizzle (conflict-free,
// verified r4+): write linear dest tid*16, global source 16B-col =
// (tid&7)^((tid>>3)&7); read slot = (ks*4+quad) ^ (l16&7).
// ---------------------------------------------------------------------------
__global__ __launch_bounds__(256, 2) void mfma_gemm(const bf16* __restrict__ A,
                                                    const bf16* __restrict__ BT,
                                                    GOuts go, int N, int K,
                                                    const int* __restrict__ flag, int cH)
{
    __shared__ __align__(16) char smem[65536];
    const int cf   = cH ? *flag : 0;
    const int tid  = threadIdx.x;
    const int lane = tid & 63;
    const int quad = lane >> 4;
    const int l16  = lane & 15;
    const int w    = tid >> 6;
    const int wm   = w >> 1, wn = w & 1;
    const int bm   = blockIdx.y * 128, bn = blockIdx.x * 128;

    int seg = 0;
    #pragma unroll
    for (int i = 1; i < 3; ++i)
        if (i < go.nseg && bn >= go.start[i]) seg = i;
    void* const dstp   = go.p[seg];
    const int  dstoff  = go.start[seg];
    const int  dstride = go.stride[seg];

    const int nkt = K >> 6;                       // K-tiles of 64 (even: K%128==0)

    // staging: linear LDS dest, inverse-swizzled global source (rule 21)
    const int sR   = tid >> 3;                    // row 0..31 within 32-row group
    const int sCol = ((tid & 7) ^ (sR & 7)) * 8;  // bf16 col: slot ^ (row&7)
    const bf16* gA = A  + (size_t)(bm + sR) * K + sCol;
    const bf16* gB = BT + (size_t)(bn + sR) * K + sCol;
    // ds_read swizzle key = row&7 = l16&7 (rows are i*16+l16, 16==0 mod 8)
    const int rxk  = l16 & 7;
    const int aOff = (wm*64 + l16) * 128;
    const int bOff = 16384 + (wn*64 + l16) * 128;

    f32x4 acc[4][4];
    #pragma unroll
    for (int i = 0; i < 4; ++i)
        #pragma unroll
        for (int j = 0; j < 4; ++j)
            acc[i][j] = (f32x4){0.f, 0.f, 0.f, 0.f};

    s16x8 af[4][2], bf[4][2];

    #define STG(buf, kt) do {                                                    \
        const int ke_ = ((kt) < nkt ? (kt) : nkt-1) * 64;                        \
        _Pragma("unroll")                                                        \
        for (int j_ = 0; j_ < 4; ++j_)                                           \
            __builtin_amdgcn_global_load_lds(                                    \
                (const __attribute__((address_space(1))) unsigned int*)          \
                    (gA + (size_t)(j_*32) * K + ke_),                            \
                (__attribute__((address_space(3))) unsigned int*)                \
                    (smem + (buf)*32768 + j_*4096 + tid*16), 16, 0, 0);          \
        _Pragma("unroll")                                                        \
        for (int j_ = 0; j_ < 4; ++j_)                                           \
            __builtin_amdgcn_global_load_lds(                                    \
                (const __attribute__((address_space(1))) unsigned int*)          \
                    (gB + (size_t)(j_*32) * K + ke_),                            \
                (__attribute__((address_space(3))) unsigned int*)                \
                    (smem + (buf)*32768 + 16384 + j_*4096 + tid*16), 16, 0, 0);  \
    } while (0)

    #define LD(buf) do {                                                         \
        _Pragma("unroll")                                                        \
        for (int i_ = 0; i_ < 4; ++i_)                                           \
            _Pragma("unroll")                                                    \
            for (int ks_ = 0; ks_ < 2; ++ks_)                                    \
                af[i_][ks_] = *(const s16x8*)(smem + (buf)*32768 + aOff          \
                              + i_*2048 + ((((ks_<<2)|quad) ^ rxk) << 4));       \
        _Pragma("unroll")                                                        \
        for (int j_ = 0; j_ < 4; ++j_)                                           \
            _Pragma("unroll")                                                    \
            for (int ks_ = 0; ks_ < 2; ++ks_)                                    \
                bf[j_][ks_] = *(const s16x8*)(smem + (buf)*32768 + bOff          \
                              + j_*2048 + ((((ks_<<2)|quad) ^ rxk) << 4));       \
    } while (0)

    #define MM do {                                                              \
        __builtin_amdgcn_s_setprio(1);                                           \
        _Pragma("unroll")                                                        \
        for (int i_ = 0; i_ < 4; ++i_)                                           \
            _Pragma("unroll")                                                    \
            for (int j_ = 0; j_ < 4; ++j_)                                       \
                _Pragma("unroll")                                                \
                for (int ks_ = 0; ks_ < 2; ++ks_)                                \
                    acc[i_][j_] = __builtin_amdgcn_mfma_f32_16x16x32_bf16(       \
                        af[i_][ks_], bf[j_][ks_], acc[i_][j_], 0, 0, 0);         \
        __builtin_amdgcn_s_setprio(0);                                           \
    } while (0)

    #define DRAIN asm volatile("s_waitcnt vmcnt(0)" ::: "memory");               \
                  __builtin_amdgcn_s_barrier()

    STG(0, 0);
    DRAIN;

    for (int t = 0; t < nkt; t += 2) {
        STG(1, t+1);      // issue-early: overlaps LD+MFMA below
        LD(0);
        MM;
        DRAIN;            // buf1 staged + buf0 consumed by all waves
        STG(0, t+2);      // last iter: clamped duplicate, never read
        LD(1);
        MM;
        DRAIN;
    }

    #undef STG
    #undef LD
    #undef MM
    #undef DRAIN

    #pragma unroll
    for (int i = 0; i < 4; ++i) {
        const int crow = bm + wm*64 + i*16 + quad*4;
        #pragma unroll
        for (int r = 0; r < 4; ++r) {
            #pragma unroll
            for (int j = 0; j < 4; ++j) {
                const int ccol = bn + wn*64 + j*16 + l16;
                if (ccol < N) {
                    const size_t idx = (size_t)(crow + r) * dstride + (ccol - dstoff);
                    if (cf) ((float*)dstp)[idx] = acc[i][j][r];
                    else    ((bf16*)dstp)[idx] = f2b(acc[i][j][r]);
                }
            }
        }
    }
}

// ---------------------------------------------------------------------------
// In-place RMSNorm over rows of X [rows, NPER*256] (internal bf16)
// ---------------------------------------------------------------------------
template<int NPER>
__global__ __launch_bounds__(256) void rms_kernel(bf16* __restrict__ X,
                                                  const void* __restrict__ w,
                                                  const int* __restrict__ flag)
{
    const int wf = *flag;
    const int ncols = NPER * 256;
    __shared__ float red[4];
    const int row = blockIdx.x;
    const int tid = threadIdx.x;
    bf16* xr = X + (size_t)row * ncols;
    float vals[NPER];
    float ss = 0.f;
    #pragma unroll
    for (int i = 0; i < NPER; ++i) {
        float v = b2f(xr[tid + i*256]);
        vals[i] = v; ss += v*v;
    }
    #pragma unroll
    for (int off = 32; off; off >>= 1) ss += __shfl_down(ss, off, 64);
    if ((tid & 63) == 0) red[tid >> 6] = ss;
    __syncthreads();
    const float tot = red[0]+red[1]+red[2]+red[3];
    const float rs  = rsqrtf(tot / (float)ncols + 1e-6f);
    #pragma unroll
    for (int i = 0; i < NPER; ++i) {
        const int c = tid + i*256;
        xr[c] = f2b(vals[i] * rs * ldS(w, c, wf));
    }
}

// ---------------------------------------------------------------------------
// k_pe: in-place RMSNorm over 64 cols + RoPE
// ---------------------------------------------------------------------------
__global__ __launch_bounds__(64) void kpe_rms_rope(bf16* __restrict__ X,
                                                   const void* __restrict__ w,
                                                   const int* __restrict__ flag)
{
    const int wf   = *flag;
    const int row  = blockIdx.x;
    const int t    = row & (T_ - 1);
    const int lane = threadIdx.x;
    bf16* xr = X + (size_t)row * RD_;
    const float v = b2f(xr[lane]);
    float ss = v * v;
    #pragma unroll
    for (int off = 32; off; off >>= 1) ss += __shfl_down(ss, off, 64);
    ss = __shfl(ss, 0, 64);
    const float rs = rsqrtf(ss / 64.f + 1e-6f);
    const float xn = v * rs * ldS(w, lane, wf);
    const int   i  = lane & 31;
    const float freq = powf(10000.f, -(float)(2*i) / 64.f);
    const float ang  = (float)t * freq;
    const float s = sinf(ang), c = cosf(ang);
    const float other = __shfl_xor(xn, 32, 64);
    const float o = (lane < 32) ? (xn * c - other * s) : (other * s + xn * c);
    xr[lane] = f2b(o);
}

// ---------------------------------------------------------------------------
// q_pe RoPE in-place: X [B*T, H*64]
// ---------------------------------------------------------------------------
__global__ __launch_bounds__(256) void qpe_rope(bf16* __restrict__ X)
{
    const int row = blockIdx.x;
    const int t   = row & (T_ - 1);
    bf16* xr = X + (size_t)row * (H_ * RD_);
    const int tid = threadIdx.x;
    #pragma unroll
    for (int pp = 0; pp < 2; ++pp) {
        const int p  = tid + pp * 256;
        const int hh = p >> 5;
        const int i  = p & 31;
        const int i0 = hh * 64 + i;
        const int i1 = i0 + 32;
        const float x1 = b2f(xr[i0]), x2 = b2f(xr[i1]);
        const float freq = powf(10000.f, -(float)(2*i) / 64.f);
        const float ang  = (float)t * freq;
        const float s = sinf(ang), c = cosf(ang);
        xr[i0] = f2b(x1 * c - x2 * s);
        xr[i1] = f2b(x1 * s + x2 * c);
    }
}

// ---------------------------------------------------------------------------
// Flash-style MFMA attention v6: v5 (verified @113-114us, rounds 2-8)
// + MFMA ones-row row-sum: Vt extended to 144 d-rows; row 128 = all 1.0,
// rows 129-143 = 0. Since o_new = o_old*alpha + P.V, the d=128 output
// column satisfies exactly the l_run recurrence -> the row-sum falls out
// of the PV MFMA. Removes the per-tile 4-level sum shfl_xor tree (16 shfl
// + 32 adds + l_run/rs bookkeeping); adds 2 MFMA/tile + one epilogue
// broadcast. LDS 50KB -> still 3 blocks/CU.
// ---------------------------------------------------------------------------
__global__ __launch_bounds__(256, 2) void flash_attn(const bf16* __restrict__ qnop,
                                                     const bf16* __restrict__ qpe,
                                                     const bf16* __restrict__ kv,
                                                     const bf16* __restrict__ kpe,
                                                     const bf16* __restrict__ vT,
                                                     bf16* __restrict__ y)
{
    __shared__ __align__(16) short Klds[64 * 192];
    __shared__ __align__(16) short Vt[144 * 64];    // rows 128..143: ones/zeros ext
    __shared__ __align__(16) short Plds[4][16 * 64];

    const int h   = blockIdx.x;
    const int qt  = 31 - (int)blockIdx.y;          // heavy blocks dispatched first
    const int b   = blockIdx.z;
    const int q0  = qt * 64;
    const int tid = threadIdx.x;
    const int w    = tid >> 6;
    const int lane = tid & 63;
    const int quad = lane >> 4;
    const int l16  = lane & 15;
    const int rk   = l16 & 7;
    const int rkp  = (l16 ^ (l16 >> 3)) & 7;
    const int row0 = q0 + w * 16;
    const size_t bT = (size_t)b * T_;
    const int bh  = b * H_ + h;

    const int kR = tid >> 4, kS = tid & 15;
    const int pR = tid >> 3, pS = tid & 7;
    const int vD = tid >> 3, vS = tid & 7;

    const bf16* gK = kv  + (bT + kR) * (H_*256) + h*128 + kS*8;
    const bf16* gP = kpe + (bT + pR) * RD_ + pS*8;
    const bf16* gV = vT  + ((size_t)bh*HD_ + vD) * T_ + vS*8;

    short* const wK = &Klds[kR*192 + ((kS ^ (kR & 7)) << 3)];
    short* const wP = &Klds[pR*192 + 128 + ((pS ^ (pR & 7)) << 3)];
    short* const wV = &Vt[vD*64 + ((vS ^ (vD & 7)) << 3)];

    // one-time init of extension rows (row 128 = 1.0 across all cols ->
    // swizzle-invariant; rows 129..143 = 0). Covered by the loop's first
    // lgkmcnt(0)+s_barrier before any read.
    {
        const int ri = tid >> 4;            // 0..15
        const int ci = (tid & 15) * 4;      // 0..60
        const short vv = (ri == 0) ? (short)0x3F80 : (short)0;
        Vt[(128 + ri)*64 + ci + 0] = vv;
        Vt[(128 + ri)*64 + ci + 1] = vv;
        Vt[(128 + ri)*64 + ci + 2] = vv;
        Vt[(128 + ri)*64 + ci + 3] = vv;
    }

    s16x8 aq[6];
    {
        const size_t r = bT + row0 + l16;
        const bf16* qn = qnop + r * (H_*128) + h*128 + quad*8;
        #pragma unroll
        for (int kk = 0; kk < 4; ++kk) aq[kk] = *(const s16x8*)(qn + kk*32);
        const bf16* qp = qpe + r * (H_*64) + h*64 + quad*8;
        aq[4] = *(const s16x8*)(qp);
        aq[5] = *(const s16x8*)(qp + 32);
    }

    f32x4 o[9];                      // o[8] = row-sum accumulator (l)
    #pragma unroll
    for (int i = 0; i < 9; ++i) o[i] = (f32x4){0.f,0.f,0.f,0.f};
    float m_run[4] = {-1e30f,-1e30f,-1e30f,-1e30f};

    uint4 k0, k1, k2, k3, p0, p1, v0, v1, v2, v3;
    #define PF(J0) do {                                                     \
        const bf16* a_ = gK + (size_t)(J0) * (H_*256);                      \
        k0 = *(const uint4*)(a_);                                           \
        k1 = *(const uint4*)(a_ + 16*(H_*256));                             \
        k2 = *(const uint4*)(a_ + 32*(H_*256));                             \
        k3 = *(const uint4*)(a_ + 48*(H_*256));                             \
        const bf16* p_ = gP + (size_t)(J0) * RD_;                           \
        p0 = *(const uint4*)(p_);                                           \
        p1 = *(const uint4*)(p_ + 32*RD_);                                  \
        const bf16* v_ = gV + (J0);                                         \
        v0 = *(const uint4*)(v_);                                           \
        v1 = *(const uint4*)(v_ + 32*T_);                                   \
        v2 = *(const uint4*)(v_ + 64*T_);                                   \
        v3 = *(const uint4*)(v_ + 96*T_);                                   \
    } while (0)

    PF(0);

    const int ntiles = qt + 1;
    for (int it = 0; it < ntiles; ++it) {
        const int j0 = it * 64;
        asm volatile("s_waitcnt lgkmcnt(0)\n\ts_barrier" ::: "memory");

        *(uint4*)(wK)          = k0;
        *(uint4*)(wK + 16*192) = k1;
        *(uint4*)(wK + 32*192) = k2;
        *(uint4*)(wK + 48*192) = k3;
        *(uint4*)(wP)          = p0;
        *(uint4*)(wP + 32*192) = p1;
        *(uint4*)(wV)          = v0;
        *(uint4*)(wV + 32*64)  = v1;
        *(uint4*)(wV + 64*64)  = v2;
        *(uint4*)(wV + 96*64)  = v3;

        if (it + 1 < ntiles) PF(j0 + 64);

        asm volatile("s_waitcnt lgkmcnt(0)\n\ts_barrier" ::: "memory");

        if (j0 <= row0 + 15) {
            const bool needmask = (j0 + 63 > row0);
            f32x4 s[4];
            #pragma unroll
            for (int nsub = 0; nsub < 4; ++nsub) {
                f32x4 acc = (f32x4){0.f,0.f,0.f,0.f};
                #pragma unroll
                for (int kk = 0; kk < 6; ++kk) {
                    const s16x8 bk = *(const s16x8*)&Klds[(nsub*16 + l16)*192
                                        + ((((kk << 2) | quad) ^ rk) << 3)];
                    acc = __builtin_amdgcn_mfma_f32_16x16x32_bf16(aq[kk], bk, acc, 0, 0, 0);
                }
                #pragma unroll
                for (int reg = 0; reg < 4; ++reg) acc[reg] *= SCALE_;
                s[nsub] = acc;
            }
            if (needmask) {
                #pragma unroll
                for (int nsub = 0; nsub < 4; ++nsub)
                    #pragma unroll
                    for (int reg = 0; reg < 4; ++reg) {
                        const int col = j0 + nsub*16 + l16;
                        const int row = row0 + quad*4 + reg;
                        if (col > row) s[nsub][reg] = -1e30f;
                    }
            }
            float mt[4], alpha[4];
            #pragma unroll
            for (int reg = 0; reg < 4; ++reg)
                mt[reg] = fmaxf(fmaxf(s[0][reg], s[1][reg]), fmaxf(s[2][reg], s[3][reg]));
            #pragma unroll
            for (int d = 1; d < 16; d <<= 1)
                #pragma unroll
                for (int reg = 0; reg < 4; ++reg)
                    mt[reg] = fmaxf(mt[reg], __shfl_xor(mt[reg], d, 64));
            #pragma unroll
            for (int reg = 0; reg < 4; ++reg) {
                const float mnew = fmaxf(m_run[reg], mt[reg]);
                alpha[reg] = __expf(m_run[reg] - mnew);
                m_run[reg] = mnew;
            }
            #pragma unroll
            for (int nsub = 0; nsub < 4; ++nsub)
                #pragma unroll
                for (int reg = 0; reg < 4; ++reg)
                    s[nsub][reg] = __expf(s[nsub][reg] - m_run[reg]);

            #pragma unroll
            for (int nsub = 0; nsub < 4; ++nsub)
                #pragma unroll
                for (int reg = 0; reg < 4; ++reg) {
                    const bf16 pv = f2b(s[nsub][reg]);
                    const int prow = (quad << 2) + reg;
                    const int pk   = (prow ^ (prow >> 3)) & 7;
                    const int pby  = ((nsub << 5) + (l16 << 1)) ^ (pk << 4);
                    Plds[w][prow*64 + (pby >> 1)] = *(const short*)&pv;
                }
            #pragma unroll
            for (int n2 = 0; n2 < 9; ++n2)
                #pragma unroll
                for (int reg = 0; reg < 4; ++reg)
                    o[n2][reg] *= alpha[reg];

            const s16x8 ap0 = *(const s16x8*)&Plds[w][l16*64 + (((quad    ) ^ rkp) << 3)];
            const s16x8 ap1 = *(const s16x8*)&Plds[w][l16*64 + (((quad | 4) ^ rkp) << 3)];
            #pragma unroll
            for (int n2 = 0; n2 < 9; ++n2) {
                const s16x8 bv0 = *(const s16x8*)&Vt[(n2*16 + l16)*64 + (((quad    ) ^ rk) << 3)];
                const s16x8 bv1 = *(const s16x8*)&Vt[(n2*16 + l16)*64 + (((quad | 4) ^ rk) << 3)];
                o[n2] = __builtin_amdgcn_mfma_f32_16x16x32_bf16(ap0, bv0, o[n2], 0, 0, 0);
                o[n2] = __builtin_amdgcn_mfma_f32_16x16x32_bf16(ap1, bv1, o[n2], 0, 0, 0);
            }
        }
    }
    #undef PF

    #pragma unroll
    for (int reg = 0; reg < 4; ++reg) {
        // l lives at lane (quad*16) of o[8] (d=128 column); broadcast in-quad
        const float l   = __shfl(o[8][reg], (lane & 48), 64);
        const float inv = 1.f / l;
        const size_t r = bT + row0 + quad*4 + reg;
        bf16* yr = y + r * (H_*128) + h*128 + l16;
        #pragma unroll
        for (int n2 = 0; n2 < 8; ++n2)
            yr[n2*16] = f2b(o[n2][reg] * inv);
    }
}

// ---------------------------------------------------------------------------
extern "C" void kernel_launch(void* const* d_in, const int* in_sizes, int n_in,
                              void* d_out, int out_size, void* d_ws, size_t ws_size,
                              hipStream_t stream)
{
    const void* x         = d_in[0];
    const void* Wq_down   = d_in[1];
    const void* q_norm_w  = d_in[2];
    const void* Wq_up     = d_in[3];
    const void* Wq_pe     = d_in[4];
    const void* Wkv_down  = d_in[5];
    const void* kv_norm_w = d_in[6];
    const void* Wkv_up    = d_in[7];
    const void* Wk_pe     = d_in[8];
    const void* kpe_nw    = d_in[9];
    const void* Wo        = d_in[10];

    char* ws = (char*)d_ws;
    int*  flag = (int*)(ws + 0);
    bf16* xb   = (bf16*)(ws + 256);        // [4096,2048] — dead after x-GEMM; reused as vT
    bf16* cQ   = (bf16*)(ws + 16777472);   // [4096,1536] — dead after q-GEMM; reused as P3/P4
    bf16* cKV  = (bf16*)(ws + 29360384);   // [4096, 512]
    bf16* kpeb = (bf16*)(ws + 33554688);   // [4096,  64]
    bf16* qnop = (bf16*)(ws + 34078976);   // [4096,2048]
    bf16* qpeb = (bf16*)(ws + 50856192);   // [4096,1024]
    bf16* kvb  = (bf16*)(ws + 59244800);   // [4096,4096] — written late; holds P1/P2 early
    bf16* yb   = (bf16*)(ws + 92799232);   // [4096,2048]  (end 109,576,448)

    // weight arenas (lifetime-safe overlays):
    bf16* P1 = kvb;                            // [2176][2048] x-weights^T (8.9 MB)
    bf16* P2 = (bf16*)((char*)kvb + 8912896);  // [3072][1536] q-weights^T (9.4 MB)
    bf16* P3 = cQ;                             // [4096][512]  Wkv_up^T    (4.2 MB)
    bf16* P4 = (bf16*)((char*)cQ + 4194304);   // [2048][2048] Wo^T        (8.4 MB)
    bf16* vT = xb;                             // [B*H][128][2048] V^T

    const dim3 blk(256);

    detect_kernel<<<1, dim3(64), 0, stream>>>((const unsigned short*)x, flag);
    convert_kernel<<<(B_*T_*C_)/(256*8), blk, 0, stream>>>(x, xb, B_*T_*C_, flag);

    // ---- batched transpose #1: x-path + q-path weights ----
    {
        TBatch tb;
        tb.d[0] = { Wq_down,  P1,               C_,  QLR_,     0, QLR_/32 };    // 3072 blks
        tb.d[1] = { Wkv_down, P1 + 1536*2048,   C_,  KLR_,  3072, KLR_/32 };    // 1024
        tb.d[2] = { Wk_pe,    P1 + 2048*2048,   C_,  RD_,   4096, RD_/32  };    //  128
        tb.d[3] = { Wq_up,    P2,               QLR_, 2048, 4224, 2048/32 };    // 3072
        tb.d[4] = { Wq_pe,    P2 + 2048*1536,   QLR_, 1024, 7296, 1024/32 };    // 1536
        tb.nseg = 5;
        transpose_batch<<<8832, blk, 0, stream>>>(tb, flag);
    }

    // ---- fused x-projection GEMM: x @ [Wq_down | Wkv_down | Wk_pe] ----
    {
        GOuts go; go.nseg = 3;
        go.p[0]=cQ;   go.start[0]=0;    go.stride[0]=QLR_;
        go.p[1]=cKV;  go.start[1]=1536; go.stride[1]=KLR_;
        go.p[2]=kpeb; go.start[2]=2048; go.stride[2]=RD_;
        mfma_gemm<<<dim3(17, 32), blk, 0, stream>>>(xb, P1, go, 2112, C_, flag, 0);
    }
    rms_kernel<6><<<B_*T_, blk, 0, stream>>>(cQ, q_norm_w, flag);
    rms_kernel<2><<<B_*T_, blk, 0, stream>>>(cKV, kv_norm_w, flag);
    kpe_rms_rope<<<B_*T_, dim3(64), 0, stream>>>(kpeb, kpe_nw, flag);

    // ---- fused q-projection GEMM: cQ @ [Wq_up | Wq_pe] ----
    {
        GOuts go; go.nseg = 2;
        go.p[0]=qnop; go.start[0]=0;    go.stride[0]=H_*HD_;
        go.p[1]=qpeb; go.start[1]=2048; go.stride[1]=H_*RD_;
        go.p[2]=nullptr; go.start[2]=0; go.stride[2]=0;
        mfma_gemm<<<dim3(24, 32), blk, 0, stream>>>(cQ, P2, go, 3072, QLR_, flag, 0);
    }
    qpe_rope<<<B_*T_, blk, 0, stream>>>(qpeb);

    // ---- batched transpose #2: Wkv_up, Wo (cQ now dead) ----
    {
        TBatch tb;
        tb.d[0] = { Wkv_up, P3, KLR_, H_*2*HD_,    0, (H_*2*HD_)/32 };  // 2048 blks
        tb.d[1] = { Wo,     P4, H_*HD_, C_,     2048, C_/32 };          // 4096
        tb.d[2] = tb.d[1]; tb.d[3] = tb.d[1]; tb.d[4] = tb.d[1];
        tb.nseg = 2;
        transpose_batch<<<6144, blk, 0, stream>>>(tb, flag);
    }

    // ---- kv up-projection, then V transpose (xb dead) ----
    {
        GOuts go; go.nseg = 1;
        go.p[0]=kvb; go.start[0]=0; go.stride[0]=H_*2*HD_;
        go.p[1]=nullptr; go.start[1]=0; go.stride[1]=0;
        go.p[2]=nullptr; go.start[2]=0; go.stride[2]=0;
        mfma_gemm<<<dim3(32, 32), blk, 0, stream>>>(cKV, P3, go, H_*2*HD_, KLR_, flag, 0);
    }
    transpose_v_kernel<<<dim3((H_*HD_)/32, (B_*T_)/32), blk, 0, stream>>>(kvb, vT);

    // ---- attention ----
    flash_attn<<<dim3(H_, T_/64, B_), blk, 0, stream>>>(qnop, qpeb, kvb, kpeb, vT, yb);

    // ---- output projection (dtype of d_out per flag) ----
    {
        GOuts go; go.nseg = 1;
        go.p[0]=d_out; go.start[0]=0; go.stride[0]=C_;
        go.p[1]=nullptr; go.start[1]=0; go.stride[1]=0;
        go.p[2]=nullptr; go.start[2]=0; go.stride[2]=0;
        mfma_gemm<<<dim3(C_/128, 32), blk, 0, stream>>>(yb, P4, go, C_, H_*HD_, flag, 1);
    }
}